// Round 15
// baseline (179.671 us; speedup 1.0000x reference)
//
#include <hip/hip_runtime.h>

typedef unsigned short u16;
typedef unsigned int   u32;
typedef __bf16 bf16x8 __attribute__((ext_vector_type(8)));
typedef float  f32x4  __attribute__((ext_vector_type(4)));

#define DEVI __device__ __forceinline__

DEVI u16 f2bf(float f) {
    union { float f; u32 u; } c; c.f = f;
    u32 u = c.u;
    u32 r = (u + 0x7fffu + ((u >> 16) & 1u)) >> 16;
    return (u16)r;
}
DEVI float bf2f(u16 v) {
    union { u32 u; float f; } c; c.u = ((u32)v) << 16;
    return c.f;
}

DEVI void gload16(const void* g, void* l) {
    __builtin_amdgcn_global_load_lds(
        (const __attribute__((address_space(1))) void*)g,
        (__attribute__((address_space(3))) void*)l, 16, 0, 0);
}

// ---------------- 256x256 GEMM, 2 phases per K-tile (frozen r13/r14) -------
// LDS 128KB: buffer q at q*32768 (u16). Halves (16KB, [128 rows][64 K] bf16):
// A0 @+0, A1 @+8192, B0 @+16384, B1 @+24576. st_16x32 swizzle:
// u16 off(r,k) = r*64 + (k ^ (((r>>2)&1)<<4)); DMA dest linear, global
// source column pre-swizzled (rule 21). vmcnt gates before closing barriers
// (vmcnt per-wave; barrier globalizes — round-3 rule).

#define VMW(N)  asm volatile("s_waitcnt vmcnt(" #N ")" ::: "memory")
#define LGKM0   asm volatile("s_waitcnt lgkmcnt(0)" ::: "memory")
#define BAR     __builtin_amdgcn_s_barrier()
#define SP1     __builtin_amdgcn_s_setprio(1)
#define SP0     __builtin_amdgcn_s_setprio(0)
#define SCB     __builtin_amdgcn_sched_barrier(0)

DEVI void stage_half(const u16* g, u16* slot, int tid) {
    const int r = tid >> 3;                                  // 0..63
    const int ks = ((tid & 7) << 3) ^ (((tid >> 5) & 1) << 4);
    gload16(g + (long)r * 1024 + ks, slot + tid * 8);
    gload16(g + (long)(r + 64) * 1024 + ks, slot + 4096 + tid * 8);
}

DEVI f32x4 mfma(const bf16x8& a, const bf16x8& b, const f32x4& c) {
    return __builtin_amdgcn_mfma_f32_16x16x32_bf16(a, b, c, 0, 0, 0);
}

#define PH2(Q, MB, READB, STG, GATE)                                         \
    {                                                                        \
        if (READB) {                                                         \
            _Pragma("unroll")                                                \
            for (int n = 0; n < 4; ++n) {                                    \
                bh[n][0] = *(const bf16x8*)(lds + (Q) + bbase + n * 1024);   \
                bh[n][1] = *(const bf16x8*)(lds + (Q) + bbase + n * 1024 + 32); \
            }                                                                \
        }                                                                    \
        bf16x8 a0k0 = *(const bf16x8*)(lds + (Q) + abase + (MB) * 2048);     \
        bf16x8 a0k1 = *(const bf16x8*)(lds + (Q) + abase + (MB) * 2048 + 32); \
        bf16x8 a1k0 = *(const bf16x8*)(lds + (Q) + abase + (MB) * 2048 + 1024); \
        bf16x8 a1k1 = *(const bf16x8*)(lds + (Q) + abase + (MB) * 2048 + 1056); \
        STG;                                                                 \
        BAR;                                                                 \
        LGKM0; SCB;                                                          \
        SP1;                                                                 \
        _Pragma("unroll")                                                    \
        for (int n = 0; n < 4; ++n) {                                        \
            acc[(MB) * 2][n]     = mfma(a0k0, bh[n][0], acc[(MB) * 2][n]);   \
            acc[(MB) * 2][n]     = mfma(a0k1, bh[n][1], acc[(MB) * 2][n]);   \
            acc[(MB) * 2 + 1][n] = mfma(a1k0, bh[n][0], acc[(MB) * 2 + 1][n]); \
            acc[(MB) * 2 + 1][n] = mfma(a1k1, bh[n][1], acc[(MB) * 2 + 1][n]); \
        }                                                                    \
        {                                                                    \
            const int M2 = (MB) + 1;                                         \
            bf16x8 c0k0 = *(const bf16x8*)(lds + (Q) + abase + M2 * 2048);   \
            bf16x8 c0k1 = *(const bf16x8*)(lds + (Q) + abase + M2 * 2048 + 32); \
            bf16x8 c1k0 = *(const bf16x8*)(lds + (Q) + abase + M2 * 2048 + 1024); \
            bf16x8 c1k1 = *(const bf16x8*)(lds + (Q) + abase + M2 * 2048 + 1056); \
            _Pragma("unroll")                                                \
            for (int n = 0; n < 4; ++n) {                                    \
                acc[M2 * 2][n]     = mfma(c0k0, bh[n][0], acc[M2 * 2][n]);   \
                acc[M2 * 2][n]     = mfma(c0k1, bh[n][1], acc[M2 * 2][n]);   \
                acc[M2 * 2 + 1][n] = mfma(c1k0, bh[n][0], acc[M2 * 2 + 1][n]); \
                acc[M2 * 2 + 1][n] = mfma(c1k1, bh[n][1], acc[M2 * 2 + 1][n]); \
            }                                                                \
        }                                                                    \
        SP0;                                                                 \
        GATE;                                                                \
        BAR;                                                                 \
    }

#define NOP do {} while (0)
#define AH(t, h) (Ab + (long)(h) * 131072 + (t) * 64)
#define BH(t, h) (Bb + (long)(h) * 131072 + (t) * 64)

DEVI void pipe256(const u16* Ab, const u16* Bb, u16* lds,
                  f32x4 (&acc)[8][4], int tid) {
    const int lane = tid & 63;
    const int wm = (tid >> 6) >> 2, wn = (tid >> 6) & 3;
    const int kswz = ((lane >> 4) << 3) ^ (((lane >> 2) & 1) << 4);
    const int abase = wm * 8192 + (lane & 15) * 64 + kswz;
    const int bbase = 16384 + (wn >> 1) * 8192 + ((wn & 1) * 64 + (lane & 15)) * 64 + kswz;

    stage_half(AH(0, 0), lds + 0,             tid);
    stage_half(AH(0, 1), lds + 8192,          tid);
    stage_half(BH(0, 0), lds + 16384,         tid);
    stage_half(BH(0, 1), lds + 24576,         tid);
    stage_half(BH(1, 0), lds + 32768 + 16384, tid);
    stage_half(BH(1, 1), lds + 32768 + 24576, tid);
    VMW(4); BAR;                 // T0 landed; T1.B (4 loads) in flight

    bf16x8 bh[4][2];

#pragma unroll 1
    for (int j = 0; j < 7; ++j) {
        const int T = 2 * j;
        PH2(0, 0, 1,
            { stage_half(AH(T + 1, 0), lds + 32768, tid);
              stage_half(AH(T + 1, 1), lds + 32768 + 8192, tid); }, NOP);
        PH2(0, 2, 0,
            { stage_half(BH(T + 2, 0), lds + 16384, tid);
              stage_half(BH(T + 2, 1), lds + 24576, tid); }, VMW(4));
        PH2(32768, 0, 1,
            { stage_half(AH(T + 2, 0), lds + 0, tid);
              stage_half(AH(T + 2, 1), lds + 8192, tid); }, NOP);
        PH2(32768, 2, 0,
            { stage_half(BH(T + 3, 0), lds + 32768 + 16384, tid);
              stage_half(BH(T + 3, 1), lds + 32768 + 24576, tid); }, VMW(4));
    }
    PH2(0, 0, 1,
        { stage_half(AH(15, 0), lds + 32768, tid);
          stage_half(AH(15, 1), lds + 32768 + 8192, tid); }, NOP);
    PH2(0, 2, 0, NOP, VMW(0));
    PH2(32768, 0, 1, NOP, NOP);
    PH2(32768, 2, 0, NOP, NOP);
}

// ------- gate GEMM + fused sigmoid-gate + fused per-chunk scan (scanA) ------

__global__ __launch_bounds__(512, 1) void k_gemm_cat8(
    const u16* __restrict__ A, const u16* __restrict__ Bcat,
    const float* __restrict__ gb, const float* __restrict__ ib,
    u32* __restrict__ ab, float2* __restrict__ cAB) {
    __shared__ __align__(16) u16 lds[65536];
    const int tid = threadIdx.x, lane = tid & 63;
    const int wm = (tid >> 6) >> 2, wn = (tid >> 6) & 3;

    int fid = (int)blockIdx.y * 8 + (int)blockIdx.x;
    int swz = (fid & 7) * 64 + (fid >> 3);
    const long bn = swz & 7, bm = swz >> 3;

    f32x4 acc[8][4] = {};
    pipe256(A + bm * 256 * 1024, Bcat + bn * 256 * 1024, lds, acc, tid);

    const long rbase = bm * 256 + wm * 128;
    const int chbase = (int)bn * 128 + wn * 32;
    float sA[2][8], sB[2][8];
#pragma unroll
    for (int t = 0; t < 2; ++t) {
        int ch = chbase + t * 16 + (lane & 15);
        float g0 = gb[ch], i0 = ib[ch];
#pragma unroll
        for (int m = 0; m < 8; ++m) {
            long row = rbase + m * 16 + ((lane >> 4) << 2);
            float Aseg = 1.0f, Bseg = 0.0f;
#pragma unroll
            for (int i = 0; i < 4; ++i) {
                float pg = acc[m][2 * t][i] + g0;
                float pi = acc[m][2 * t + 1][i] + i0;
                float aa = 1.0f / (1.0f + __expf(-pg));
                float bb = (1.0f - aa) * pi;
                u16 au = f2bf(aa), bu = f2bf(bb);
                ab[(row + i) * 1024 + ch] = (u32)au | ((u32)bu << 16);
                float ar = bf2f(au), br = bf2f(bu);
                Aseg = ar * Aseg;
                Bseg = ar * Bseg + br;
            }
            sA[t][m] = Aseg;
            sB[t][m] = Bseg;
        }
    }
#pragma unroll
    for (int t = 0; t < 2; ++t) {
#pragma unroll
        for (int c2 = 0; c2 < 2; ++c2) {
            float Ac = 1.0f, Bc = 0.0f;
#pragma unroll
            for (int mm = 0; mm < 4; ++mm) {
                int m = c2 * 4 + mm;
#pragma unroll
                for (int q = 0; q < 4; ++q) {
                    float Aq = __shfl(sA[t][m], (lane & 15) + q * 16);
                    float Bq = __shfl(sB[t][m], (lane & 15) + q * 16);
                    Ac = Aq * Ac;
                    Bc = Aq * Bc + Bq;
                }
            }
            if ((lane >> 4) == 0) {
                long gc = (rbase >> 6) + c2;
                int ch = chbase + t * 16 + (lane & 15);
                cAB[gc * 1024 + ch] = make_float2(Ac, Bc);
            }
        }
    }
}

// -------- final GEMM: out = h @ out_w + x + out_b (x residual as bf16) ------

__global__ __launch_bounds__(512, 1) void k_gemm_out8(
    const u16* __restrict__ A, const u16* __restrict__ Bt,
    const u16* __restrict__ xbf, const float* __restrict__ ob,
    float* __restrict__ out) {
    __shared__ __align__(16) u16 lds[65536];
    const int tid = threadIdx.x, lane = tid & 63;
    const int wm = (tid >> 6) >> 2, wn = (tid >> 6) & 3;

    int fid = (int)blockIdx.y * 4 + (int)blockIdx.x;
    int swz = (fid & 7) * 32 + (fid >> 3);
    const long bn = swz & 3, bm = swz >> 2;

    f32x4 acc[8][4] = {};
    pipe256(A + bm * 256 * 1024, Bt + bn * 256 * 1024, lds, acc, tid);

    const long rbase = bm * 256 + wm * 128;
    const int cbase = (int)bn * 256 + wn * 64;
#pragma unroll
    for (int n = 0; n < 4; ++n) {
        int col = cbase + n * 16 + (lane & 15);
        float o0 = ob[col];
#pragma unroll
        for (int m = 0; m < 8; ++m) {
            long row = rbase + m * 16 + ((lane >> 4) << 2);
#pragma unroll
            for (int i = 0; i < 4; ++i) {
                long o = (row + i) * 1024 + col;
                out[o] = acc[m][n][i] + o0 + bf2f(xbf[o]);
            }
        }
    }
}

// ------------- fused prep: cvt_x + transpose_cat + transpose_bf -------------

__global__ __launch_bounds__(256) void k_prep(
    const float4* __restrict__ x4, uint2* __restrict__ xb2,
    const float* __restrict__ gw, const float* __restrict__ iw,
    u16* __restrict__ catW, const float* __restrict__ ow,
    u16* __restrict__ owT) {
    __shared__ float t[32][33];
    int bid = blockIdx.x;
    if (bid < 16384) {
        int i = bid * 256 + threadIdx.x;
        float4 v = x4[i];
        uint2 r;
        r.x = (u32)f2bf(v.x) | ((u32)f2bf(v.y) << 16);
        r.y = (u32)f2bf(v.z) | ((u32)f2bf(v.w) << 16);
        xb2[i] = r;
        return;
    }
    int xi = threadIdx.x & 31, y = threadIdx.x >> 5;
    if (bid < 18432) {
        int q = bid - 16384;
        int c0 = (q & 31) * 32, r0 = ((q >> 5) & 31) * 32, z = q >> 10;
        const float* w = z ? iw : gw;
        for (int i = y; i < 32; i += 8) t[i][xi] = w[(size_t)(r0 + i) * 1024 + c0 + xi];
        __syncthreads();
        for (int i = y; i < 32; i += 8) {
            int ch = c0 + i;
            int r = ((ch >> 4) << 5) | (z << 4) | (ch & 15);
            catW[(size_t)r * 1024 + r0 + xi] = f2bf(t[xi][i]);
        }
    } else {
        int q = bid - 18432;
        int c0 = (q & 31) * 32, r0 = (q >> 5) * 32;
        for (int i = y; i < 32; i += 8) t[i][xi] = ow[(size_t)(r0 + i) * 1024 + c0 + xi];
        __syncthreads();
        for (int i = y; i < 32; i += 8)
            owT[(size_t)(c0 + i) * 1024 + r0 + xi] = f2bf(t[xi][i]);
    }
}

// ------------- scan replay with inline prefix (scanB folded in) -------------
// Block (c, bt): incoming state = fold of cAB[bt, 0..c) (L2-resident, 2MB),
// then replay 64 steps from packed ab and write h (bf16).

__global__ __launch_bounds__(256) void k_scanC(const u32* __restrict__ ab,
                                               const float2* __restrict__ cAB,
                                               u16* __restrict__ hout) {
    int e = blockIdx.x * 256 + threadIdx.x;
    int c = blockIdx.y, bt = blockIdx.z;
    // inline prefix: H_in = fold_{j<c} (A_j, B_j)
    float H = 0.f;
    long sb = (long)bt * 64 * 1024 + e;
    for (int j = 0; j < c; ++j) {
        float2 v = cAB[sb + (long)j * 1024];
        H = v.x * H + v.y;
    }
    long base = ((long)bt * 4096 + c * 64) * 1024 + e;
#pragma unroll 4
    for (int i = 0; i < 64; ++i) {
        u32 v = ab[base + (long)i * 1024];
        H = bf2f((u16)v) * H + bf2f((u16)(v >> 16));
        hout[base + (long)i * 1024] = f2bf(H);
    }
}

// ---------------- launch ----------------

extern "C" void kernel_launch(void* const* d_in, const int* in_sizes, int n_in,
                              void* d_out, int out_size, void* d_ws, size_t ws_size,
                              hipStream_t stream) {
    const float* x      = (const float*)d_in[0];
    const float* gate_w = (const float*)d_in[1];
    const float* gate_b = (const float*)d_in[2];
    const float* inp_w  = (const float*)d_in[3];
    const float* inp_b  = (const float*)d_in[4];
    const float* out_w  = (const float*)d_in[5];
    const float* out_b  = (const float*)d_in[6];
    float* out = (float*)d_out;

    const int Bsz = 4, S = 4096, Din = 1024, Dst = 1024;
    const int M = Bsz * S;                 // 16384

    // workspace layout (bytes)
    char* w = (char*)d_ws;
    u16* xb      = (u16*)(w);                // 33,554,432  x bf16
    u16* catW    = (u16*)(w + 33554432);     //  4,194,304  [gate;inp] interleaved ^T
    u16* owT     = (u16*)(w + 37748736);     //  2,097,152  out_w^T bf16
    u16* hbf     = (u16*)(w + 39845888);     // 33,554,432  scan_out bf16
    float2* cAB  = (float2*)(w + 73400320);  //  2,097,152  chunk (A,H) pairs
    // total 75,497,472 B

    // packed ab lives in d_out (67,108,864 B); overwritten by final GEMM.
    u32* ab = (u32*)d_out;

    // 1. fused prep (cvt + both transposes)
    k_prep<<<19456, 256, 0, stream>>>((const float4*)x, (uint2*)xb,
                                      gate_w, inp_w, catW, out_w, owT);

    // 2. fused concat GEMM -> packed ab + per-chunk scan composition
    k_gemm_cat8<<<dim3(8, M / 256), 512, 0, stream>>>(xb, catW, gate_b, inp_b, ab, cAB);

    // 3. scan replay (inline prefix) -> h (bf16)
    k_scanC<<<dim3(4, 64, Bsz), 256, 0, stream>>>(ab, cAB, hbf);

    // 4. final GEMM: out = h @ out_w + x + out_b
    k_gemm_out8<<<dim3(4, M / 256), 512, 0, stream>>>(hbf, owT, xb, out_b, out);
}

// Round 16
// 175.410 us; speedup vs baseline: 1.0243x; 1.0243x over previous
//
#include <hip/hip_runtime.h>

typedef unsigned short u16;
typedef unsigned int   u32;
typedef __bf16 bf16x8 __attribute__((ext_vector_type(8)));
typedef float  f32x4  __attribute__((ext_vector_type(4)));

#define DEVI __device__ __forceinline__

DEVI u16 f2bf(float f) {
    union { float f; u32 u; } c; c.f = f;
    u32 u = c.u;
    u32 r = (u + 0x7fffu + ((u >> 16) & 1u)) >> 16;
    return (u16)r;
}
DEVI float bf2f(u16 v) {
    union { u32 u; float f; } c; c.u = ((u32)v) << 16;
    return c.f;
}

DEVI void gload16(const void* g, void* l) {
    __builtin_amdgcn_global_load_lds(
        (const __attribute__((address_space(1))) void*)g,
        (__attribute__((address_space(3))) void*)l, 16, 0, 0);
}

// ---------------- 256x256 GEMM, 2 phases per K-tile (frozen) ----------------
// LDS 128KB: buffer q at q*32768 (u16). Halves (16KB, [128 rows][64 K] bf16):
// A0 @+0, A1 @+8192, B0 @+16384, B1 @+24576. st_16x32 swizzle:
// u16 off(r,k) = r*64 + (k ^ (((r>>2)&1)<<4)); DMA dest linear, global
// source column pre-swizzled (rule 21). vmcnt gates before closing barriers
// (vmcnt per-wave; barrier globalizes — round-3 rule).

#define VMW(N)  asm volatile("s_waitcnt vmcnt(" #N ")" ::: "memory")
#define LGKM0   asm volatile("s_waitcnt lgkmcnt(0)" ::: "memory")
#define BAR     __builtin_amdgcn_s_barrier()
#define SP1     __builtin_amdgcn_s_setprio(1)
#define SP0     __builtin_amdgcn_s_setprio(0)
#define SCB     __builtin_amdgcn_sched_barrier(0)

DEVI void stage_half(const u16* g, u16* slot, int tid) {
    const int r = tid >> 3;                                  // 0..63
    const int ks = ((tid & 7) << 3) ^ (((tid >> 5) & 1) << 4);
    gload16(g + (long)r * 1024 + ks, slot + tid * 8);
    gload16(g + (long)(r + 64) * 1024 + ks, slot + 4096 + tid * 8);
}

DEVI f32x4 mfma(const bf16x8& a, const bf16x8& b, const f32x4& c) {
    return __builtin_amdgcn_mfma_f32_16x16x32_bf16(a, b, c, 0, 0, 0);
}

#define PH2(Q, MB, READB, STG, GATE)                                         \
    {                                                                        \
        if (READB) {                                                         \
            _Pragma("unroll")                                                \
            for (int n = 0; n < 4; ++n) {                                    \
                bh[n][0] = *(const bf16x8*)(lds + (Q) + bbase + n * 1024);   \
                bh[n][1] = *(const bf16x8*)(lds + (Q) + bbase + n * 1024 + 32); \
            }                                                                \
        }                                                                    \
        bf16x8 a0k0 = *(const bf16x8*)(lds + (Q) + abase + (MB) * 2048);     \
        bf16x8 a0k1 = *(const bf16x8*)(lds + (Q) + abase + (MB) * 2048 + 32); \
        bf16x8 a1k0 = *(const bf16x8*)(lds + (Q) + abase + (MB) * 2048 + 1024); \
        bf16x8 a1k1 = *(const bf16x8*)(lds + (Q) + abase + (MB) * 2048 + 1056); \
        STG;                                                                 \
        BAR;                                                                 \
        LGKM0; SCB;                                                          \
        SP1;                                                                 \
        _Pragma("unroll")                                                    \
        for (int n = 0; n < 4; ++n) {                                        \
            acc[(MB) * 2][n]     = mfma(a0k0, bh[n][0], acc[(MB) * 2][n]);   \
            acc[(MB) * 2][n]     = mfma(a0k1, bh[n][1], acc[(MB) * 2][n]);   \
            acc[(MB) * 2 + 1][n] = mfma(a1k0, bh[n][0], acc[(MB) * 2 + 1][n]); \
            acc[(MB) * 2 + 1][n] = mfma(a1k1, bh[n][1], acc[(MB) * 2 + 1][n]); \
        }                                                                    \
        {                                                                    \
            const int M2 = (MB) + 1;                                         \
            bf16x8 c0k0 = *(const bf16x8*)(lds + (Q) + abase + M2 * 2048);   \
            bf16x8 c0k1 = *(const bf16x8*)(lds + (Q) + abase + M2 * 2048 + 32); \
            bf16x8 c1k0 = *(const bf16x8*)(lds + (Q) + abase + M2 * 2048 + 1024); \
            bf16x8 c1k1 = *(const bf16x8*)(lds + (Q) + abase + M2 * 2048 + 1056); \
            _Pragma("unroll")                                                \
            for (int n = 0; n < 4; ++n) {                                    \
                acc[M2 * 2][n]     = mfma(c0k0, bh[n][0], acc[M2 * 2][n]);   \
                acc[M2 * 2][n]     = mfma(c0k1, bh[n][1], acc[M2 * 2][n]);   \
                acc[M2 * 2 + 1][n] = mfma(c1k0, bh[n][0], acc[M2 * 2 + 1][n]); \
                acc[M2 * 2 + 1][n] = mfma(c1k1, bh[n][1], acc[M2 * 2 + 1][n]); \
            }                                                                \
        }                                                                    \
        SP0;                                                                 \
        GATE;                                                                \
        BAR;                                                                 \
    }

#define NOP do {} while (0)
#define AH(t, h) (Ab + (long)(h) * 131072 + (t) * 64)
#define BH(t, h) (Bb + (long)(h) * 131072 + (t) * 64)

DEVI void pipe256(const u16* Ab, const u16* Bb, u16* lds,
                  f32x4 (&acc)[8][4], int tid) {
    const int lane = tid & 63;
    const int wm = (tid >> 6) >> 2, wn = (tid >> 6) & 3;
    const int kswz = ((lane >> 4) << 3) ^ (((lane >> 2) & 1) << 4);
    const int abase = wm * 8192 + (lane & 15) * 64 + kswz;
    const int bbase = 16384 + (wn >> 1) * 8192 + ((wn & 1) * 64 + (lane & 15)) * 64 + kswz;

    stage_half(AH(0, 0), lds + 0,             tid);
    stage_half(AH(0, 1), lds + 8192,          tid);
    stage_half(BH(0, 0), lds + 16384,         tid);
    stage_half(BH(0, 1), lds + 24576,         tid);
    stage_half(BH(1, 0), lds + 32768 + 16384, tid);
    stage_half(BH(1, 1), lds + 32768 + 24576, tid);
    VMW(4); BAR;                 // T0 landed; T1.B (4 loads) in flight

    bf16x8 bh[4][2];

#pragma unroll 1
    for (int j = 0; j < 7; ++j) {
        const int T = 2 * j;
        PH2(0, 0, 1,
            { stage_half(AH(T + 1, 0), lds + 32768, tid);
              stage_half(AH(T + 1, 1), lds + 32768 + 8192, tid); }, NOP);
        PH2(0, 2, 0,
            { stage_half(BH(T + 2, 0), lds + 16384, tid);
              stage_half(BH(T + 2, 1), lds + 24576, tid); }, VMW(4));
        PH2(32768, 0, 1,
            { stage_half(AH(T + 2, 0), lds + 0, tid);
              stage_half(AH(T + 2, 1), lds + 8192, tid); }, NOP);
        PH2(32768, 2, 0,
            { stage_half(BH(T + 3, 0), lds + 32768 + 16384, tid);
              stage_half(BH(T + 3, 1), lds + 32768 + 24576, tid); }, VMW(4));
    }
    PH2(0, 0, 1,
        { stage_half(AH(15, 0), lds + 32768, tid);
          stage_half(AH(15, 1), lds + 32768 + 8192, tid); }, NOP);
    PH2(0, 2, 0, NOP, VMW(0));
    PH2(32768, 0, 1, NOP, NOP);
    PH2(32768, 2, 0, NOP, NOP);
}

// ------- gate GEMM + fused sigmoid-gate + fused per-chunk scan (scanA) ------

__global__ __launch_bounds__(512, 1) void k_gemm_cat8(
    const u16* __restrict__ A, const u16* __restrict__ Bcat,
    const float* __restrict__ gb, const float* __restrict__ ib,
    u32* __restrict__ ab, float2* __restrict__ cAB) {
    __shared__ __align__(16) u16 lds[65536];
    const int tid = threadIdx.x, lane = tid & 63;
    const int wm = (tid >> 6) >> 2, wn = (tid >> 6) & 3;

    int fid = (int)blockIdx.y * 8 + (int)blockIdx.x;
    int swz = (fid & 7) * 64 + (fid >> 3);
    const long bn = swz & 7, bm = swz >> 3;

    f32x4 acc[8][4] = {};
    pipe256(A + bm * 256 * 1024, Bcat + bn * 256 * 1024, lds, acc, tid);

    const long rbase = bm * 256 + wm * 128;
    const int chbase = (int)bn * 128 + wn * 32;
    float sA[2][8], sB[2][8];
#pragma unroll
    for (int t = 0; t < 2; ++t) {
        int ch = chbase + t * 16 + (lane & 15);
        float g0 = gb[ch], i0 = ib[ch];
#pragma unroll
        for (int m = 0; m < 8; ++m) {
            long row = rbase + m * 16 + ((lane >> 4) << 2);
            float Aseg = 1.0f, Bseg = 0.0f;
#pragma unroll
            for (int i = 0; i < 4; ++i) {
                float pg = acc[m][2 * t][i] + g0;
                float pi = acc[m][2 * t + 1][i] + i0;
                float aa = 1.0f / (1.0f + __expf(-pg));
                float bb = (1.0f - aa) * pi;
                u16 au = f2bf(aa), bu = f2bf(bb);
                ab[(row + i) * 1024 + ch] = (u32)au | ((u32)bu << 16);
                float ar = bf2f(au), br = bf2f(bu);
                Aseg = ar * Aseg;
                Bseg = ar * Bseg + br;
            }
            sA[t][m] = Aseg;
            sB[t][m] = Bseg;
        }
    }
#pragma unroll
    for (int t = 0; t < 2; ++t) {
#pragma unroll
        for (int c2 = 0; c2 < 2; ++c2) {
            float Ac = 1.0f, Bc = 0.0f;
#pragma unroll
            for (int mm = 0; mm < 4; ++mm) {
                int m = c2 * 4 + mm;
#pragma unroll
                for (int q = 0; q < 4; ++q) {
                    float Aq = __shfl(sA[t][m], (lane & 15) + q * 16);
                    float Bq = __shfl(sB[t][m], (lane & 15) + q * 16);
                    Ac = Aq * Ac;
                    Bc = Aq * Bc + Bq;
                }
            }
            if ((lane >> 4) == 0) {
                long gc = (rbase >> 6) + c2;
                int ch = chbase + t * 16 + (lane & 15);
                cAB[gc * 1024 + ch] = make_float2(Ac, Bc);
            }
        }
    }
}

// -------- final GEMM: out = h @ out_w + x + out_b (x residual as bf16) ------

__global__ __launch_bounds__(512, 1) void k_gemm_out8(
    const u16* __restrict__ A, const u16* __restrict__ Bt,
    const u16* __restrict__ xbf, const float* __restrict__ ob,
    float* __restrict__ out) {
    __shared__ __align__(16) u16 lds[65536];
    const int tid = threadIdx.x, lane = tid & 63;
    const int wm = (tid >> 6) >> 2, wn = (tid >> 6) & 3;

    int fid = (int)blockIdx.y * 4 + (int)blockIdx.x;
    int swz = (fid & 7) * 32 + (fid >> 3);
    const long bn = swz & 3, bm = swz >> 2;

    f32x4 acc[8][4] = {};
    pipe256(A + bm * 256 * 1024, Bt + bn * 256 * 1024, lds, acc, tid);

    const long rbase = bm * 256 + wm * 128;
    const int cbase = (int)bn * 256 + wn * 64;
#pragma unroll
    for (int n = 0; n < 4; ++n) {
        int col = cbase + n * 16 + (lane & 15);
        float o0 = ob[col];
#pragma unroll
        for (int m = 0; m < 8; ++m) {
            long row = rbase + m * 16 + ((lane >> 4) << 2);
#pragma unroll
            for (int i = 0; i < 4; ++i) {
                long o = (row + i) * 1024 + col;
                out[o] = acc[m][n][i] + o0 + bf2f(xbf[o]);
            }
        }
    }
}

// ------------- fused prep: cvt_x + transpose_cat + transpose_bf -------------

__global__ __launch_bounds__(256) void k_prep(
    const float4* __restrict__ x4, uint2* __restrict__ xb2,
    const float* __restrict__ gw, const float* __restrict__ iw,
    u16* __restrict__ catW, const float* __restrict__ ow,
    u16* __restrict__ owT) {
    __shared__ float t[32][33];
    int bid = blockIdx.x;
    if (bid < 16384) {
        int i = bid * 256 + threadIdx.x;
        float4 v = x4[i];
        uint2 r;
        r.x = (u32)f2bf(v.x) | ((u32)f2bf(v.y) << 16);
        r.y = (u32)f2bf(v.z) | ((u32)f2bf(v.w) << 16);
        xb2[i] = r;
        return;
    }
    int xi = threadIdx.x & 31, y = threadIdx.x >> 5;
    if (bid < 18432) {
        int q = bid - 16384;
        int c0 = (q & 31) * 32, r0 = ((q >> 5) & 31) * 32, z = q >> 10;
        const float* w = z ? iw : gw;
        for (int i = y; i < 32; i += 8) t[i][xi] = w[(size_t)(r0 + i) * 1024 + c0 + xi];
        __syncthreads();
        for (int i = y; i < 32; i += 8) {
            int ch = c0 + i;
            int r = ((ch >> 4) << 5) | (z << 4) | (ch & 15);
            catW[(size_t)r * 1024 + r0 + xi] = f2bf(t[xi][i]);
        }
    } else {
        int q = bid - 18432;
        int c0 = (q & 31) * 32, r0 = (q >> 5) * 32;
        for (int i = y; i < 32; i += 8) t[i][xi] = ow[(size_t)(r0 + i) * 1024 + c0 + xi];
        __syncthreads();
        for (int i = y; i < 32; i += 8)
            owT[(size_t)(c0 + i) * 1024 + r0 + xi] = f2bf(t[xi][i]);
    }
}

// ---------------- chunked affine scan phases B & C ----------------

__global__ __launch_bounds__(256) void k_scanB(const float2* __restrict__ cAB,
                                               float* __restrict__ hin) {
    int e = blockIdx.x * 256 + threadIdx.x;
    int bt = blockIdx.y;
    float H = 0.f;
#pragma unroll
    for (int c = 0; c < 64; ++c) {
        long s = ((long)bt * 64 + c) * 1024 + e;
        hin[s] = H;
        float2 v = cAB[s];
        H = v.x * H + v.y;
    }
}

__global__ __launch_bounds__(256) void k_scanC(const u32* __restrict__ ab,
                                               const float* __restrict__ hin,
                                               u16* __restrict__ hout) {
    int e = blockIdx.x * 256 + threadIdx.x;
    int c = blockIdx.y, bt = blockIdx.z;
    long base = ((long)bt * 4096 + c * 64) * 1024 + e;
    float H = hin[((long)bt * 64 + c) * 1024 + e];
#pragma unroll 4
    for (int i = 0; i < 64; ++i) {
        u32 v = ab[base + (long)i * 1024];
        H = bf2f((u16)v) * H + bf2f((u16)(v >> 16));
        hout[base + (long)i * 1024] = f2bf(H);
    }
}

// ---------------- launch ----------------

extern "C" void kernel_launch(void* const* d_in, const int* in_sizes, int n_in,
                              void* d_out, int out_size, void* d_ws, size_t ws_size,
                              hipStream_t stream) {
    const float* x      = (const float*)d_in[0];
    const float* gate_w = (const float*)d_in[1];
    const float* gate_b = (const float*)d_in[2];
    const float* inp_w  = (const float*)d_in[3];
    const float* inp_b  = (const float*)d_in[4];
    const float* out_w  = (const float*)d_in[5];
    const float* out_b  = (const float*)d_in[6];
    float* out = (float*)d_out;

    const int Bsz = 4, S = 4096, Din = 1024, Dst = 1024;
    const int M = Bsz * S;                 // 16384

    // workspace layout (bytes)
    char* w = (char*)d_ws;
    u16* xb      = (u16*)(w);                // 33,554,432  x bf16
    u16* catW    = (u16*)(w + 33554432);     //  4,194,304  [gate;inp] interleaved ^T
    u16* owT     = (u16*)(w + 37748736);     //  2,097,152  out_w^T bf16
    u16* hbf     = (u16*)(w + 39845888);     // 33,554,432  scan_out bf16
    float2* cAB  = (float2*)(w + 73400320);  //  2,097,152  chunk (A,H) pairs
    float* hin   = (float*)(w + 75497472);   //  1,048,576  chunk incoming states
    // total 76,546,048 B

    // packed ab lives in d_out (67,108,864 B); overwritten by final GEMM.
    u32* ab = (u32*)d_out;

    // 1. fused prep (cvt + both transposes)
    k_prep<<<19456, 256, 0, stream>>>((const float4*)x, (uint2*)xb,
                                      gate_w, inp_w, catW, out_w, owT);

    // 2. fused concat GEMM -> packed ab + per-chunk scan composition
    k_gemm_cat8<<<dim3(8, M / 256), 512, 0, stream>>>(xb, catW, gate_b, inp_b, ab, cAB);

    // 3. scan combine + replay -> h (bf16)
    k_scanB<<<dim3(4, Bsz), 256, 0, stream>>>(cAB, hin);
    k_scanC<<<dim3(4, 64, Bsz), 256, 0, stream>>>(ab, hin, hbf);

    // 4. final GEMM: out = h @ out_w + x + out_b
    k_gemm_out8<<<dim3(4, M / 256), 512, 0, stream>>>(hbf, owT, xb, out_b, out);
}

// Round 17
// 173.552 us; speedup vs baseline: 1.0353x; 1.0107x over previous
//
#include <hip/hip_runtime.h>

typedef unsigned short u16;
typedef unsigned int   u32;
typedef __bf16 bf16x8 __attribute__((ext_vector_type(8)));
typedef float  f32x4  __attribute__((ext_vector_type(4)));

#define DEVI __device__ __forceinline__

DEVI u16 f2bf(float f) {
    union { float f; u32 u; } c; c.f = f;
    u32 u = c.u;
    u32 r = (u + 0x7fffu + ((u >> 16) & 1u)) >> 16;
    return (u16)r;
}
DEVI float bf2f(u16 v) {
    union { u32 u; float f; } c; c.u = ((u32)v) << 16;
    return c.f;
}

DEVI void gload16(const void* g, void* l) {
    __builtin_amdgcn_global_load_lds(
        (const __attribute__((address_space(1))) void*)g,
        (__attribute__((address_space(3))) void*)l, 16, 0, 0);
}

// ---------------- 256x256 GEMM, 2 phases per K-tile ----------------
// LDS 128KB: buffer q at q*32768 (u16). Halves (16KB, [128 rows][64 K] bf16):
// A0 @+0, A1 @+8192, B0 @+16384, B1 @+24576.
// 3-bit chunk swizzle (upgraded from 1-bit st_16x32): a row is 64 u16 =
// exactly one 32-bank sweep, so bank = ((k^swz)/2)%32 — row contributes
// nothing. Physical 16B chunk p holds logical chunk p ^ (row&7):
//   stage: dest linear (tid*16B), SOURCE chunk = (tid&7) ^ ((tid>>3)&7)
//   reads: kA = ((lane>>4) ^ (lane&7))<<3, kB = kA^32  (row&7 == lane&7
//   for every A/B fragment row; rows r and r+64 share r&7).
// Each ds_read_b128 now lands 8 words on each of 32 banks (= wave64 floor)
// vs 16 words on 16 banks with the 1-bit swizzle.
// vmcnt gates before closing barriers (vmcnt per-wave; barrier globalizes).

#define VMW(N)  asm volatile("s_waitcnt vmcnt(" #N ")" ::: "memory")
#define LGKM0   asm volatile("s_waitcnt lgkmcnt(0)" ::: "memory")
#define BAR     __builtin_amdgcn_s_barrier()
#define SP1     __builtin_amdgcn_s_setprio(1)
#define SP0     __builtin_amdgcn_s_setprio(0)
#define SCB     __builtin_amdgcn_sched_barrier(0)

DEVI void stage_half(const u16* g, u16* slot, int tid) {
    const int r = tid >> 3;                                  // 0..63
    const int ks = (((tid & 7) ^ (r & 7)) << 3);             // 3-bit pre-swizzle
    gload16(g + (long)r * 1024 + ks, slot + tid * 8);
    gload16(g + (long)(r + 64) * 1024 + ks, slot + 4096 + tid * 8);
}

DEVI f32x4 mfma(const bf16x8& a, const bf16x8& b, const f32x4& c) {
    return __builtin_amdgcn_mfma_f32_16x16x32_bf16(a, b, c, 0, 0, 0);
}

#define PH2(Q, MB, READB, STG, GATE)                                         \
    {                                                                        \
        if (READB) {                                                         \
            _Pragma("unroll")                                                \
            for (int n = 0; n < 4; ++n) {                                    \
                bh[n][0] = *(const bf16x8*)(lds + (Q) + bbase + n * 1024 + kA); \
                bh[n][1] = *(const bf16x8*)(lds + (Q) + bbase + n * 1024 + kB); \
            }                                                                \
        }                                                                    \
        bf16x8 a0k0 = *(const bf16x8*)(lds + (Q) + abase + (MB) * 2048 + kA); \
        bf16x8 a0k1 = *(const bf16x8*)(lds + (Q) + abase + (MB) * 2048 + kB); \
        bf16x8 a1k0 = *(const bf16x8*)(lds + (Q) + abase + (MB) * 2048 + 1024 + kA); \
        bf16x8 a1k1 = *(const bf16x8*)(lds + (Q) + abase + (MB) * 2048 + 1024 + kB); \
        STG;                                                                 \
        BAR;                                                                 \
        LGKM0; SCB;                                                          \
        SP1;                                                                 \
        _Pragma("unroll")                                                    \
        for (int n = 0; n < 4; ++n) {                                        \
            acc[(MB) * 2][n]     = mfma(a0k0, bh[n][0], acc[(MB) * 2][n]);   \
            acc[(MB) * 2][n]     = mfma(a0k1, bh[n][1], acc[(MB) * 2][n]);   \
            acc[(MB) * 2 + 1][n] = mfma(a1k0, bh[n][0], acc[(MB) * 2 + 1][n]); \
            acc[(MB) * 2 + 1][n] = mfma(a1k1, bh[n][1], acc[(MB) * 2 + 1][n]); \
        }                                                                    \
        {                                                                    \
            const int M2 = (MB) + 1;                                         \
            bf16x8 c0k0 = *(const bf16x8*)(lds + (Q) + abase + M2 * 2048 + kA); \
            bf16x8 c0k1 = *(const bf16x8*)(lds + (Q) + abase + M2 * 2048 + kB); \
            bf16x8 c1k0 = *(const bf16x8*)(lds + (Q) + abase + M2 * 2048 + 1024 + kA); \
            bf16x8 c1k1 = *(const bf16x8*)(lds + (Q) + abase + M2 * 2048 + 1024 + kB); \
            _Pragma("unroll")                                                \
            for (int n = 0; n < 4; ++n) {                                    \
                acc[M2 * 2][n]     = mfma(c0k0, bh[n][0], acc[M2 * 2][n]);   \
                acc[M2 * 2][n]     = mfma(c0k1, bh[n][1], acc[M2 * 2][n]);   \
                acc[M2 * 2 + 1][n] = mfma(c1k0, bh[n][0], acc[M2 * 2 + 1][n]); \
                acc[M2 * 2 + 1][n] = mfma(c1k1, bh[n][1], acc[M2 * 2 + 1][n]); \
            }                                                                \
        }                                                                    \
        SP0;                                                                 \
        GATE;                                                                \
        BAR;                                                                 \
    }

#define NOP do {} while (0)
#define AH(t, h) (Ab + (long)(h) * 131072 + (t) * 64)
#define BH(t, h) (Bb + (long)(h) * 131072 + (t) * 64)

DEVI void pipe256(const u16* Ab, const u16* Bb, u16* lds,
                  f32x4 (&acc)[8][4], int tid) {
    const int lane = tid & 63;
    const int wm = (tid >> 6) >> 2, wn = (tid >> 6) & 3;
    const int kA = (((lane >> 4) ^ (lane & 7)) << 3);
    const int kB = kA ^ 32;
    const int abase = wm * 8192 + (lane & 15) * 64;
    const int bbase = 16384 + (wn >> 1) * 8192 + ((wn & 1) * 64 + (lane & 15)) * 64;

    stage_half(AH(0, 0), lds + 0,             tid);
    stage_half(AH(0, 1), lds + 8192,          tid);
    stage_half(BH(0, 0), lds + 16384,         tid);
    stage_half(BH(0, 1), lds + 24576,         tid);
    stage_half(BH(1, 0), lds + 32768 + 16384, tid);
    stage_half(BH(1, 1), lds + 32768 + 24576, tid);
    VMW(4); BAR;                 // T0 landed; T1.B (4 loads) in flight

    bf16x8 bh[4][2];

#pragma unroll 1
    for (int j = 0; j < 7; ++j) {
        const int T = 2 * j;
        PH2(0, 0, 1,
            { stage_half(AH(T + 1, 0), lds + 32768, tid);
              stage_half(AH(T + 1, 1), lds + 32768 + 8192, tid); }, NOP);
        PH2(0, 2, 0,
            { stage_half(BH(T + 2, 0), lds + 16384, tid);
              stage_half(BH(T + 2, 1), lds + 24576, tid); }, VMW(4));
        PH2(32768, 0, 1,
            { stage_half(AH(T + 2, 0), lds + 0, tid);
              stage_half(AH(T + 2, 1), lds + 8192, tid); }, NOP);
        PH2(32768, 2, 0,
            { stage_half(BH(T + 3, 0), lds + 32768 + 16384, tid);
              stage_half(BH(T + 3, 1), lds + 32768 + 24576, tid); }, VMW(4));
    }
    PH2(0, 0, 1,
        { stage_half(AH(15, 0), lds + 32768, tid);
          stage_half(AH(15, 1), lds + 32768 + 8192, tid); }, NOP);
    PH2(0, 2, 0, NOP, VMW(0));
    PH2(32768, 0, 1, NOP, NOP);
    PH2(32768, 2, 0, NOP, NOP);
}

// ------- gate GEMM + fused sigmoid-gate + fused per-chunk scan (scanA) ------

__global__ __launch_bounds__(512, 1) void k_gemm_cat8(
    const u16* __restrict__ A, const u16* __restrict__ Bcat,
    const float* __restrict__ gb, const float* __restrict__ ib,
    u32* __restrict__ ab, float2* __restrict__ cAB) {
    __shared__ __align__(16) u16 lds[65536];
    const int tid = threadIdx.x, lane = tid & 63;
    const int wm = (tid >> 6) >> 2, wn = (tid >> 6) & 3;

    int fid = (int)blockIdx.y * 8 + (int)blockIdx.x;
    int swz = (fid & 7) * 64 + (fid >> 3);
    const long bn = swz & 7, bm = swz >> 3;

    f32x4 acc[8][4] = {};
    pipe256(A + bm * 256 * 1024, Bcat + bn * 256 * 1024, lds, acc, tid);

    const long rbase = bm * 256 + wm * 128;
    const int chbase = (int)bn * 128 + wn * 32;
    float sA[2][8], sB[2][8];
#pragma unroll
    for (int t = 0; t < 2; ++t) {
        int ch = chbase + t * 16 + (lane & 15);
        float g0 = gb[ch], i0 = ib[ch];
#pragma unroll
        for (int m = 0; m < 8; ++m) {
            long row = rbase + m * 16 + ((lane >> 4) << 2);
            float Aseg = 1.0f, Bseg = 0.0f;
#pragma unroll
            for (int i = 0; i < 4; ++i) {
                float pg = acc[m][2 * t][i] + g0;
                float pi = acc[m][2 * t + 1][i] + i0;
                float aa = 1.0f / (1.0f + __expf(-pg));
                float bb = (1.0f - aa) * pi;
                u16 au = f2bf(aa), bu = f2bf(bb);
                ab[(row + i) * 1024 + ch] = (u32)au | ((u32)bu << 16);
                float ar = bf2f(au), br = bf2f(bu);
                Aseg = ar * Aseg;
                Bseg = ar * Bseg + br;
            }
            sA[t][m] = Aseg;
            sB[t][m] = Bseg;
        }
    }
#pragma unroll
    for (int t = 0; t < 2; ++t) {
#pragma unroll
        for (int c2 = 0; c2 < 2; ++c2) {
            float Ac = 1.0f, Bc = 0.0f;
#pragma unroll
            for (int mm = 0; mm < 4; ++mm) {
                int m = c2 * 4 + mm;
#pragma unroll
                for (int q = 0; q < 4; ++q) {
                    float Aq = __shfl(sA[t][m], (lane & 15) + q * 16);
                    float Bq = __shfl(sB[t][m], (lane & 15) + q * 16);
                    Ac = Aq * Ac;
                    Bc = Aq * Bc + Bq;
                }
            }
            if ((lane >> 4) == 0) {
                long gc = (rbase >> 6) + c2;
                int ch = chbase + t * 16 + (lane & 15);
                cAB[gc * 1024 + ch] = make_float2(Ac, Bc);
            }
        }
    }
}

// -------- final GEMM: out = h @ out_w + x + out_b (x residual as bf16) ------

__global__ __launch_bounds__(512, 1) void k_gemm_out8(
    const u16* __restrict__ A, const u16* __restrict__ Bt,
    const u16* __restrict__ xbf, const float* __restrict__ ob,
    float* __restrict__ out) {
    __shared__ __align__(16) u16 lds[65536];
    const int tid = threadIdx.x, lane = tid & 63;
    const int wm = (tid >> 6) >> 2, wn = (tid >> 6) & 3;

    int fid = (int)blockIdx.y * 4 + (int)blockIdx.x;
    int swz = (fid & 7) * 32 + (fid >> 3);
    const long bn = swz & 3, bm = swz >> 2;

    f32x4 acc[8][4] = {};
    pipe256(A + bm * 256 * 1024, Bt + bn * 256 * 1024, lds, acc, tid);

    const long rbase = bm * 256 + wm * 128;
    const int cbase = (int)bn * 256 + wn * 64;
#pragma unroll
    for (int n = 0; n < 4; ++n) {
        int col = cbase + n * 16 + (lane & 15);
        float o0 = ob[col];
#pragma unroll
        for (int m = 0; m < 8; ++m) {
            long row = rbase + m * 16 + ((lane >> 4) << 2);
#pragma unroll
            for (int i = 0; i < 4; ++i) {
                long o = (row + i) * 1024 + col;
                out[o] = acc[m][n][i] + o0 + bf2f(xbf[o]);
            }
        }
    }
}

// ------------- fused prep: cvt_x + transpose_cat + transpose_bf -------------

__global__ __launch_bounds__(256) void k_prep(
    const float4* __restrict__ x4, uint2* __restrict__ xb2,
    const float* __restrict__ gw, const float* __restrict__ iw,
    u16* __restrict__ catW, const float* __restrict__ ow,
    u16* __restrict__ owT) {
    __shared__ float t[32][33];
    int bid = blockIdx.x;
    if (bid < 16384) {
        int i = bid * 256 + threadIdx.x;
        float4 v = x4[i];
        uint2 r;
        r.x = (u32)f2bf(v.x) | ((u32)f2bf(v.y) << 16);
        r.y = (u32)f2bf(v.z) | ((u32)f2bf(v.w) << 16);
        xb2[i] = r;
        return;
    }
    int xi = threadIdx.x & 31, y = threadIdx.x >> 5;
    if (bid < 18432) {
        int q = bid - 16384;
        int c0 = (q & 31) * 32, r0 = ((q >> 5) & 31) * 32, z = q >> 10;
        const float* w = z ? iw : gw;
        for (int i = y; i < 32; i += 8) t[i][xi] = w[(size_t)(r0 + i) * 1024 + c0 + xi];
        __syncthreads();
        for (int i = y; i < 32; i += 8) {
            int ch = c0 + i;
            int r = ((ch >> 4) << 5) | (z << 4) | (ch & 15);
            catW[(size_t)r * 1024 + r0 + xi] = f2bf(t[xi][i]);
        }
    } else {
        int q = bid - 18432;
        int c0 = (q & 31) * 32, r0 = (q >> 5) * 32;
        for (int i = y; i < 32; i += 8) t[i][xi] = ow[(size_t)(r0 + i) * 1024 + c0 + xi];
        __syncthreads();
        for (int i = y; i < 32; i += 8)
            owT[(size_t)(c0 + i) * 1024 + r0 + xi] = f2bf(t[xi][i]);
    }
}

// ---------------- chunked affine scan phases B & C ----------------

__global__ __launch_bounds__(256) void k_scanB(const float2* __restrict__ cAB,
                                               float* __restrict__ hin) {
    int e = blockIdx.x * 256 + threadIdx.x;
    int bt = blockIdx.y;
    float H = 0.f;
#pragma unroll
    for (int c = 0; c < 64; ++c) {
        long s = ((long)bt * 64 + c) * 1024 + e;
        hin[s] = H;
        float2 v = cAB[s];
        H = v.x * H + v.y;
    }
}

__global__ __launch_bounds__(256) void k_scanC(const u32* __restrict__ ab,
                                               const float* __restrict__ hin,
                                               u16* __restrict__ hout) {
    int e = blockIdx.x * 256 + threadIdx.x;
    int c = blockIdx.y, bt = blockIdx.z;
    long base = ((long)bt * 4096 + c * 64) * 1024 + e;
    float H = hin[((long)bt * 64 + c) * 1024 + e];
#pragma unroll 4
    for (int i = 0; i < 64; ++i) {
        u32 v = ab[base + (long)i * 1024];
        H = bf2f((u16)v) * H + bf2f((u16)(v >> 16));
        hout[base + (long)i * 1024] = f2bf(H);
    }
}

// ---------------- launch ----------------

extern "C" void kernel_launch(void* const* d_in, const int* in_sizes, int n_in,
                              void* d_out, int out_size, void* d_ws, size_t ws_size,
                              hipStream_t stream) {
    const float* x      = (const float*)d_in[0];
    const float* gate_w = (const float*)d_in[1];
    const float* gate_b = (const float*)d_in[2];
    const float* inp_w  = (const float*)d_in[3];
    const float* inp_b  = (const float*)d_in[4];
    const float* out_w  = (const float*)d_in[5];
    const float* out_b  = (const float*)d_in[6];
    float* out = (float*)d_out;

    const int Bsz = 4, S = 4096, Din = 1024, Dst = 1024;
    const int M = Bsz * S;                 // 16384

    // workspace layout (bytes)
    char* w = (char*)d_ws;
    u16* xb      = (u16*)(w);                // 33,554,432  x bf16
    u16* catW    = (u16*)(w + 33554432);     //  4,194,304  [gate;inp] interleaved ^T
    u16* owT     = (u16*)(w + 37748736);     //  2,097,152  out_w^T bf16
    u16* hbf     = (u16*)(w + 39845888);     // 33,554,432  scan_out bf16
    float2* cAB  = (float2*)(w + 73400320);  //  2,097,152  chunk (A,H) pairs
    float* hin   = (float*)(w + 75497472);   //  1,048,576  chunk incoming states
    // total 76,546,048 B

    // packed ab lives in d_out (67,108,864 B); overwritten by final GEMM.
    u32* ab = (u32*)d_out;

    // 1. fused prep (cvt + both transposes)
    k_prep<<<19456, 256, 0, stream>>>((const float4*)x, (uint2*)xb,
                                      gate_w, inp_w, catW, out_w, owT);

    // 2. fused concat GEMM -> packed ab + per-chunk scan composition
    k_gemm_cat8<<<dim3(8, M / 256), 512, 0, stream>>>(xb, catW, gate_b, inp_b, ab, cAB);

    // 3. scan combine + replay -> h (bf16)
    k_scanB<<<dim3(4, Bsz), 256, 0, stream>>>(cAB, hin);
    k_scanC<<<dim3(4, 64, Bsz), 256, 0, stream>>>(ab, hin, hbf);

    // 4. final GEMM: out = h @ out_w + x + out_b
    k_gemm_out8<<<dim3(4, M / 256), 512, 0, stream>>>(hbf, owT, xb, out_b, out);
}

// Round 18
// 170.945 us; speedup vs baseline: 1.0510x; 1.0152x over previous
//
#include <hip/hip_runtime.h>

typedef unsigned short u16;
typedef unsigned int   u32;
typedef __bf16 bf16x8 __attribute__((ext_vector_type(8)));
typedef float  f32x4  __attribute__((ext_vector_type(4)));

#define DEVI __device__ __forceinline__

DEVI u16 f2bf(float f) {
    union { float f; u32 u; } c; c.f = f;
    u32 u = c.u;
    u32 r = (u + 0x7fffu + ((u >> 16) & 1u)) >> 16;
    return (u16)r;
}
DEVI float bf2f(u16 v) {
    union { u32 u; float f; } c; c.u = ((u32)v) << 16;
    return c.f;
}

DEVI void gload16(const void* g, void* l) {
    __builtin_amdgcn_global_load_lds(
        (const __attribute__((address_space(1))) void*)g,
        (__attribute__((address_space(3))) void*)l, 16, 0, 0);
}

// ---------------- 256x256 GEMM, 2 phases per K-tile ----------------
// LDS 128KB: buffer q at q*32768 (u16). Halves (16KB, [128 rows][64 K] bf16):
// A0 @+0, A1 @+8192, B0 @+16384, B1 @+24576.
// 3-bit chunk swizzle (r17, measured SQ_LDS_BANK_CONFLICT = 0): physical 16B
// chunk p holds logical p ^ (row&7); stage source ks=((tid&7)^(r&7))<<3,
// reads kA=((lane>>4)^(lane&7))<<3, kB=kA^32.
// r18 change: NO explicit lgkmcnt(0) before the MFMA burst. Reads are
// compiler loads -> compiler emits counted lgkmcnt(N) per operand (m97/G7),
// so MFMAs start as operands land and overlap the remaining LDS port time
// (and other waves' reads). Rule 18 applies only to inline-asm ds_read.
// vmcnt gates before closing barriers (per-wave; barrier globalizes).

#define VMW(N)  asm volatile("s_waitcnt vmcnt(" #N ")" ::: "memory")
#define BAR     __builtin_amdgcn_s_barrier()
#define SP1     __builtin_amdgcn_s_setprio(1)
#define SP0     __builtin_amdgcn_s_setprio(0)

DEVI void stage_half(const u16* g, u16* slot, int tid) {
    const int r = tid >> 3;                                  // 0..63
    const int ks = (((tid & 7) ^ (r & 7)) << 3);             // 3-bit pre-swizzle
    gload16(g + (long)r * 1024 + ks, slot + tid * 8);
    gload16(g + (long)(r + 64) * 1024 + ks, slot + 4096 + tid * 8);
}

DEVI f32x4 mfma(const bf16x8& a, const bf16x8& b, const f32x4& c) {
    return __builtin_amdgcn_mfma_f32_16x16x32_bf16(a, b, c, 0, 0, 0);
}

#define PH2(Q, MB, READB, STG, GATE)                                         \
    {                                                                        \
        if (READB) {                                                         \
            _Pragma("unroll")                                                \
            for (int n = 0; n < 4; ++n) {                                    \
                bh[n][0] = *(const bf16x8*)(lds + (Q) + bbase + n * 1024 + kA); \
                bh[n][1] = *(const bf16x8*)(lds + (Q) + bbase + n * 1024 + kB); \
            }                                                                \
        }                                                                    \
        bf16x8 a0k0 = *(const bf16x8*)(lds + (Q) + abase + (MB) * 2048 + kA); \
        bf16x8 a0k1 = *(const bf16x8*)(lds + (Q) + abase + (MB) * 2048 + kB); \
        bf16x8 a1k0 = *(const bf16x8*)(lds + (Q) + abase + (MB) * 2048 + 1024 + kA); \
        bf16x8 a1k1 = *(const bf16x8*)(lds + (Q) + abase + (MB) * 2048 + 1024 + kB); \
        STG;                                                                 \
        BAR;                                                                 \
        SP1;                                                                 \
        _Pragma("unroll")                                                    \
        for (int n = 0; n < 4; ++n) {                                        \
            acc[(MB) * 2][n]     = mfma(a0k0, bh[n][0], acc[(MB) * 2][n]);   \
            acc[(MB) * 2][n]     = mfma(a0k1, bh[n][1], acc[(MB) * 2][n]);   \
            acc[(MB) * 2 + 1][n] = mfma(a1k0, bh[n][0], acc[(MB) * 2 + 1][n]); \
            acc[(MB) * 2 + 1][n] = mfma(a1k1, bh[n][1], acc[(MB) * 2 + 1][n]); \
        }                                                                    \
        {                                                                    \
            const int M2 = (MB) + 1;                                         \
            bf16x8 c0k0 = *(const bf16x8*)(lds + (Q) + abase + M2 * 2048 + kA); \
            bf16x8 c0k1 = *(const bf16x8*)(lds + (Q) + abase + M2 * 2048 + kB); \
            bf16x8 c1k0 = *(const bf16x8*)(lds + (Q) + abase + M2 * 2048 + 1024 + kA); \
            bf16x8 c1k1 = *(const bf16x8*)(lds + (Q) + abase + M2 * 2048 + 1024 + kB); \
            _Pragma("unroll")                                                \
            for (int n = 0; n < 4; ++n) {                                    \
                acc[M2 * 2][n]     = mfma(c0k0, bh[n][0], acc[M2 * 2][n]);   \
                acc[M2 * 2][n]     = mfma(c0k1, bh[n][1], acc[M2 * 2][n]);   \
                acc[M2 * 2 + 1][n] = mfma(c1k0, bh[n][0], acc[M2 * 2 + 1][n]); \
                acc[M2 * 2 + 1][n] = mfma(c1k1, bh[n][1], acc[M2 * 2 + 1][n]); \
            }                                                                \
        }                                                                    \
        SP0;                                                                 \
        GATE;                                                                \
        BAR;                                                                 \
    }

#define NOP do {} while (0)
#define AH(t, h) (Ab + (long)(h) * 131072 + (t) * 64)
#define BH(t, h) (Bb + (long)(h) * 131072 + (t) * 64)

DEVI void pipe256(const u16* Ab, const u16* Bb, u16* lds,
                  f32x4 (&acc)[8][4], int tid) {
    const int lane = tid & 63;
    const int wm = (tid >> 6) >> 2, wn = (tid >> 6) & 3;
    const int kA = (((lane >> 4) ^ (lane & 7)) << 3);
    const int kB = kA ^ 32;
    const int abase = wm * 8192 + (lane & 15) * 64;
    const int bbase = 16384 + (wn >> 1) * 8192 + ((wn & 1) * 64 + (lane & 15)) * 64;

    stage_half(AH(0, 0), lds + 0,             tid);
    stage_half(AH(0, 1), lds + 8192,          tid);
    stage_half(BH(0, 0), lds + 16384,         tid);
    stage_half(BH(0, 1), lds + 24576,         tid);
    stage_half(BH(1, 0), lds + 32768 + 16384, tid);
    stage_half(BH(1, 1), lds + 32768 + 24576, tid);
    VMW(4); BAR;                 // T0 landed; T1.B (4 loads) in flight

    bf16x8 bh[4][2];

#pragma unroll 1
    for (int j = 0; j < 7; ++j) {
        const int T = 2 * j;
        PH2(0, 0, 1,
            { stage_half(AH(T + 1, 0), lds + 32768, tid);
              stage_half(AH(T + 1, 1), lds + 32768 + 8192, tid); }, NOP);
        PH2(0, 2, 0,
            { stage_half(BH(T + 2, 0), lds + 16384, tid);
              stage_half(BH(T + 2, 1), lds + 24576, tid); }, VMW(4));
        PH2(32768, 0, 1,
            { stage_half(AH(T + 2, 0), lds + 0, tid);
              stage_half(AH(T + 2, 1), lds + 8192, tid); }, NOP);
        PH2(32768, 2, 0,
            { stage_half(BH(T + 3, 0), lds + 32768 + 16384, tid);
              stage_half(BH(T + 3, 1), lds + 32768 + 24576, tid); }, VMW(4));
    }
    PH2(0, 0, 1,
        { stage_half(AH(15, 0), lds + 32768, tid);
          stage_half(AH(15, 1), lds + 32768 + 8192, tid); }, NOP);
    PH2(0, 2, 0, NOP, VMW(0));
    PH2(32768, 0, 1, NOP, NOP);
    PH2(32768, 2, 0, NOP, NOP);
}

// ------- gate GEMM + fused sigmoid-gate + fused per-chunk scan (scanA) ------

__global__ __launch_bounds__(512, 1) void k_gemm_cat8(
    const u16* __restrict__ A, const u16* __restrict__ Bcat,
    const float* __restrict__ gb, const float* __restrict__ ib,
    u32* __restrict__ ab, float2* __restrict__ cAB) {
    __shared__ __align__(16) u16 lds[65536];
    const int tid = threadIdx.x, lane = tid & 63;
    const int wm = (tid >> 6) >> 2, wn = (tid >> 6) & 3;

    int fid = (int)blockIdx.y * 8 + (int)blockIdx.x;
    int swz = (fid & 7) * 64 + (fid >> 3);
    const long bn = swz & 7, bm = swz >> 3;

    f32x4 acc[8][4] = {};
    pipe256(A + bm * 256 * 1024, Bcat + bn * 256 * 1024, lds, acc, tid);

    const long rbase = bm * 256 + wm * 128;
    const int chbase = (int)bn * 128 + wn * 32;
    float sA[2][8], sB[2][8];
#pragma unroll
    for (int t = 0; t < 2; ++t) {
        int ch = chbase + t * 16 + (lane & 15);
        float g0 = gb[ch], i0 = ib[ch];
#pragma unroll
        for (int m = 0; m < 8; ++m) {
            long row = rbase + m * 16 + ((lane >> 4) << 2);
            float Aseg = 1.0f, Bseg = 0.0f;
#pragma unroll
            for (int i = 0; i < 4; ++i) {
                float pg = acc[m][2 * t][i] + g0;
                float pi = acc[m][2 * t + 1][i] + i0;
                float aa = 1.0f / (1.0f + __expf(-pg));
                float bb = (1.0f - aa) * pi;
                u16 au = f2bf(aa), bu = f2bf(bb);
                ab[(row + i) * 1024 + ch] = (u32)au | ((u32)bu << 16);
                float ar = bf2f(au), br = bf2f(bu);
                Aseg = ar * Aseg;
                Bseg = ar * Bseg + br;
            }
            sA[t][m] = Aseg;
            sB[t][m] = Bseg;
        }
    }
#pragma unroll
    for (int t = 0; t < 2; ++t) {
#pragma unroll
        for (int c2 = 0; c2 < 2; ++c2) {
            float Ac = 1.0f, Bc = 0.0f;
#pragma unroll
            for (int mm = 0; mm < 4; ++mm) {
                int m = c2 * 4 + mm;
#pragma unroll
                for (int q = 0; q < 4; ++q) {
                    float Aq = __shfl(sA[t][m], (lane & 15) + q * 16);
                    float Bq = __shfl(sB[t][m], (lane & 15) + q * 16);
                    Ac = Aq * Ac;
                    Bc = Aq * Bc + Bq;
                }
            }
            if ((lane >> 4) == 0) {
                long gc = (rbase >> 6) + c2;
                int ch = chbase + t * 16 + (lane & 15);
                cAB[gc * 1024 + ch] = make_float2(Ac, Bc);
            }
        }
    }
}

// -------- final GEMM: out = h @ out_w + x + out_b (x residual as bf16) ------

__global__ __launch_bounds__(512, 1) void k_gemm_out8(
    const u16* __restrict__ A, const u16* __restrict__ Bt,
    const u16* __restrict__ xbf, const float* __restrict__ ob,
    float* __restrict__ out) {
    __shared__ __align__(16) u16 lds[65536];
    const int tid = threadIdx.x, lane = tid & 63;
    const int wm = (tid >> 6) >> 2, wn = (tid >> 6) & 3;

    int fid = (int)blockIdx.y * 4 + (int)blockIdx.x;
    int swz = (fid & 7) * 32 + (fid >> 3);
    const long bn = swz & 3, bm = swz >> 2;

    f32x4 acc[8][4] = {};
    pipe256(A + bm * 256 * 1024, Bt + bn * 256 * 1024, lds, acc, tid);

    const long rbase = bm * 256 + wm * 128;
    const int cbase = (int)bn * 256 + wn * 64;
#pragma unroll
    for (int n = 0; n < 4; ++n) {
        int col = cbase + n * 16 + (lane & 15);
        float o0 = ob[col];
#pragma unroll
        for (int m = 0; m < 8; ++m) {
            long row = rbase + m * 16 + ((lane >> 4) << 2);
#pragma unroll
            for (int i = 0; i < 4; ++i) {
                long o = (row + i) * 1024 + col;
                out[o] = acc[m][n][i] + o0 + bf2f(xbf[o]);
            }
        }
    }
}

// ------------- fused prep: cvt_x + transpose_cat + transpose_bf -------------

__global__ __launch_bounds__(256) void k_prep(
    const float4* __restrict__ x4, uint2* __restrict__ xb2,
    const float* __restrict__ gw, const float* __restrict__ iw,
    u16* __restrict__ catW, const float* __restrict__ ow,
    u16* __restrict__ owT) {
    __shared__ float t[32][33];
    int bid = blockIdx.x;
    if (bid < 16384) {
        int i = bid * 256 + threadIdx.x;
        float4 v = x4[i];
        uint2 r;
        r.x = (u32)f2bf(v.x) | ((u32)f2bf(v.y) << 16);
        r.y = (u32)f2bf(v.z) | ((u32)f2bf(v.w) << 16);
        xb2[i] = r;
        return;
    }
    int xi = threadIdx.x & 31, y = threadIdx.x >> 5;
    if (bid < 18432) {
        int q = bid - 16384;
        int c0 = (q & 31) * 32, r0 = ((q >> 5) & 31) * 32, z = q >> 10;
        const float* w = z ? iw : gw;
        for (int i = y; i < 32; i += 8) t[i][xi] = w[(size_t)(r0 + i) * 1024 + c0 + xi];
        __syncthreads();
        for (int i = y; i < 32; i += 8) {
            int ch = c0 + i;
            int r = ((ch >> 4) << 5) | (z << 4) | (ch & 15);
            catW[(size_t)r * 1024 + r0 + xi] = f2bf(t[xi][i]);
        }
    } else {
        int q = bid - 18432;
        int c0 = (q & 31) * 32, r0 = (q >> 5) * 32;
        for (int i = y; i < 32; i += 8) t[i][xi] = ow[(size_t)(r0 + i) * 1024 + c0 + xi];
        __syncthreads();
        for (int i = y; i < 32; i += 8)
            owT[(size_t)(c0 + i) * 1024 + r0 + xi] = f2bf(t[xi][i]);
    }
}

// ---------------- chunked affine scan phases B & C ----------------

__global__ __launch_bounds__(256) void k_scanB(const float2* __restrict__ cAB,
                                               float* __restrict__ hin) {
    int e = blockIdx.x * 256 + threadIdx.x;
    int bt = blockIdx.y;
    float H = 0.f;
#pragma unroll
    for (int c = 0; c < 64; ++c) {
        long s = ((long)bt * 64 + c) * 1024 + e;
        hin[s] = H;
        float2 v = cAB[s];
        H = v.x * H + v.y;
    }
}

__global__ __launch_bounds__(256) void k_scanC(const u32* __restrict__ ab,
                                               const float* __restrict__ hin,
                                               u16* __restrict__ hout) {
    int e = blockIdx.x * 256 + threadIdx.x;
    int c = blockIdx.y, bt = blockIdx.z;
    long base = ((long)bt * 4096 + c * 64) * 1024 + e;
    float H = hin[((long)bt * 64 + c) * 1024 + e];
#pragma unroll 4
    for (int i = 0; i < 64; ++i) {
        u32 v = ab[base + (long)i * 1024];
        H = bf2f((u16)v) * H + bf2f((u16)(v >> 16));
        hout[base + (long)i * 1024] = f2bf(H);
    }
}

// ---------------- launch ----------------

extern "C" void kernel_launch(void* const* d_in, const int* in_sizes, int n_in,
                              void* d_out, int out_size, void* d_ws, size_t ws_size,
                              hipStream_t stream) {
    const float* x      = (const float*)d_in[0];
    const float* gate_w = (const float*)d_in[1];
    const float* gate_b = (const float*)d_in[2];
    const float* inp_w  = (const float*)d_in[3];
    const float* inp_b  = (const float*)d_in[4];
    const float* out_w  = (const float*)d_in[5];
    const float* out_b  = (const float*)d_in[6];
    float* out = (float*)d_out;

    const int Bsz = 4, S = 4096, Din = 1024, Dst = 1024;
    const int M = Bsz * S;                 // 16384

    // workspace layout (bytes)
    char* w = (char*)d_ws;
    u16* xb      = (u16*)(w);                // 33,554,432  x bf16
    u16* catW    = (u16*)(w + 33554432);     //  4,194,304  [gate;inp] interleaved ^T
    u16* owT     = (u16*)(w + 37748736);     //  2,097,152  out_w^T bf16
    u16* hbf     = (u16*)(w + 39845888);     // 33,554,432  scan_out bf16
    float2* cAB  = (float2*)(w + 73400320);  //  2,097,152  chunk (A,H) pairs
    float* hin   = (float*)(w + 75497472);   //  1,048,576  chunk incoming states
    // total 76,546,048 B

    // packed ab lives in d_out (67,108,864 B); overwritten by final GEMM.
    u32* ab = (u32*)d_out;

    // 1. fused prep (cvt + both transposes)
    k_prep<<<19456, 256, 0, stream>>>((const float4*)x, (uint2*)xb,
                                      gate_w, inp_w, catW, out_w, owT);

    // 2. fused concat GEMM -> packed ab + per-chunk scan composition
    k_gemm_cat8<<<dim3(8, M / 256), 512, 0, stream>>>(xb, catW, gate_b, inp_b, ab, cAB);

    // 3. scan combine + replay -> h (bf16)
    k_scanB<<<dim3(4, Bsz), 256, 0, stream>>>(cAB, hin);
    k_scanC<<<dim3(4, 64, Bsz), 256, 0, stream>>>(ab, hin, hbf);

    // 4. final GEMM: out = h @ out_w + x + out_b
    k_gemm_out8<<<dim3(4, M / 256), 512, 0, stream>>>(hbf, owT, xb, out_b, out);
}

// Round 19
// 168.259 us; speedup vs baseline: 1.0678x; 1.0160x over previous
//
#include <hip/hip_runtime.h>

typedef unsigned short u16;
typedef unsigned int   u32;
typedef __bf16 bf16x8 __attribute__((ext_vector_type(8)));
typedef float  f32x4  __attribute__((ext_vector_type(4)));

#define DEVI __device__ __forceinline__

DEVI u16 f2bf(float f) {
    union { float f; u32 u; } c; c.f = f;
    u32 u = c.u;
    u32 r = (u + 0x7fffu + ((u >> 16) & 1u)) >> 16;
    return (u16)r;
}
DEVI float bf2f(u16 v) {
    union { u32 u; float f; } c; c.u = ((u32)v) << 16;
    return c.f;
}

DEVI void gload16(const void* g, void* l) {
    __builtin_amdgcn_global_load_lds(
        (const __attribute__((address_space(1))) void*)g,
        (__attribute__((address_space(3))) void*)l, 16, 0, 0);
}

// ---------------- 256x256 GEMM, 2 phases per K-tile ----------------
// LDS 128KB: buffer q at q*32768 (u16). Halves (16KB, [128 rows][64 K] bf16):
// A0 @+0, A1 @+8192, B0 @+16384, B1 @+24576.
// 3-bit chunk swizzle (r17, measured SQ_LDS_BANK_CONFLICT = 0): physical 16B
// chunk p holds logical p ^ (row&7); stage source ks=((tid&7)^(r&7))<<3,
// reads kA=((lane>>4)^(lane&7))<<3, kB=kA^32.
// r19 change: NO opening barrier inside the phase. Audit: (1) current-buffer
// reads are ordered by the PREVIOUS closing barrier (vmcnt-gated); (2) WAR on
// stages needs only one closing barrier of separation (reads lgkm-consumed
// before MFMA, which precedes the barrier) — holds for A (1-tile-ahead) and
// B (2-tile-ahead) rotations; (3) visibility ledger unchanged (VMW(4) gates
// at each tile's phB). Waves now free-slip within a phase -> one wave's MFMA
// overlaps another's LDS-port time (sum -> max), and setprio has role
// diversity to arbitrate (T5 prerequisite).

#define VMW(N)  asm volatile("s_waitcnt vmcnt(" #N ")" ::: "memory")
#define BAR     __builtin_amdgcn_s_barrier()
#define SP1     __builtin_amdgcn_s_setprio(1)
#define SP0     __builtin_amdgcn_s_setprio(0)

DEVI void stage_half(const u16* g, u16* slot, int tid) {
    const int r = tid >> 3;                                  // 0..63
    const int ks = (((tid & 7) ^ (r & 7)) << 3);             // 3-bit pre-swizzle
    gload16(g + (long)r * 1024 + ks, slot + tid * 8);
    gload16(g + (long)(r + 64) * 1024 + ks, slot + 4096 + tid * 8);
}

DEVI f32x4 mfma(const bf16x8& a, const bf16x8& b, const f32x4& c) {
    return __builtin_amdgcn_mfma_f32_16x16x32_bf16(a, b, c, 0, 0, 0);
}

#define PH2(Q, MB, READB, STG, GATE)                                         \
    {                                                                        \
        if (READB) {                                                         \
            _Pragma("unroll")                                                \
            for (int n = 0; n < 4; ++n) {                                    \
                bh[n][0] = *(const bf16x8*)(lds + (Q) + bbase + n * 1024 + kA); \
                bh[n][1] = *(const bf16x8*)(lds + (Q) + bbase + n * 1024 + kB); \
            }                                                                \
        }                                                                    \
        bf16x8 a0k0 = *(const bf16x8*)(lds + (Q) + abase + (MB) * 2048 + kA); \
        bf16x8 a0k1 = *(const bf16x8*)(lds + (Q) + abase + (MB) * 2048 + kB); \
        bf16x8 a1k0 = *(const bf16x8*)(lds + (Q) + abase + (MB) * 2048 + 1024 + kA); \
        bf16x8 a1k1 = *(const bf16x8*)(lds + (Q) + abase + (MB) * 2048 + 1024 + kB); \
        STG;                                                                 \
        SP1;                                                                 \
        _Pragma("unroll")                                                    \
        for (int n = 0; n < 4; ++n) {                                        \
            acc[(MB) * 2][n]     = mfma(a0k0, bh[n][0], acc[(MB) * 2][n]);   \
            acc[(MB) * 2][n]     = mfma(a0k1, bh[n][1], acc[(MB) * 2][n]);   \
            acc[(MB) * 2 + 1][n] = mfma(a1k0, bh[n][0], acc[(MB) * 2 + 1][n]); \
            acc[(MB) * 2 + 1][n] = mfma(a1k1, bh[n][1], acc[(MB) * 2 + 1][n]); \
        }                                                                    \
        {                                                                    \
            const int M2 = (MB) + 1;                                         \
            bf16x8 c0k0 = *(const bf16x8*)(lds + (Q) + abase + M2 * 2048 + kA); \
            bf16x8 c0k1 = *(const bf16x8*)(lds + (Q) + abase + M2 * 2048 + kB); \
            bf16x8 c1k0 = *(const bf16x8*)(lds + (Q) + abase + M2 * 2048 + 1024 + kA); \
            bf16x8 c1k1 = *(const bf16x8*)(lds + (Q) + abase + M2 * 2048 + 1024 + kB); \
            _Pragma("unroll")                                                \
            for (int n = 0; n < 4; ++n) {                                    \
                acc[M2 * 2][n]     = mfma(c0k0, bh[n][0], acc[M2 * 2][n]);   \
                acc[M2 * 2][n]     = mfma(c0k1, bh[n][1], acc[M2 * 2][n]);   \
                acc[M2 * 2 + 1][n] = mfma(c1k0, bh[n][0], acc[M2 * 2 + 1][n]); \
                acc[M2 * 2 + 1][n] = mfma(c1k1, bh[n][1], acc[M2 * 2 + 1][n]); \
            }                                                                \
        }                                                                    \
        SP0;                                                                 \
        GATE;                                                                \
        BAR;                                                                 \
    }

#define NOP do {} while (0)
#define AH(t, h) (Ab + (long)(h) * 131072 + (t) * 64)
#define BH(t, h) (Bb + (long)(h) * 131072 + (t) * 64)

DEVI void pipe256(const u16* Ab, const u16* Bb, u16* lds,
                  f32x4 (&acc)[8][4], int tid) {
    const int lane = tid & 63;
    const int wm = (tid >> 6) >> 2, wn = (tid >> 6) & 3;
    const int kA = (((lane >> 4) ^ (lane & 7)) << 3);
    const int kB = kA ^ 32;
    const int abase = wm * 8192 + (lane & 15) * 64;
    const int bbase = 16384 + (wn >> 1) * 8192 + ((wn & 1) * 64 + (lane & 15)) * 64;

    stage_half(AH(0, 0), lds + 0,             tid);
    stage_half(AH(0, 1), lds + 8192,          tid);
    stage_half(BH(0, 0), lds + 16384,         tid);
    stage_half(BH(0, 1), lds + 24576,         tid);
    stage_half(BH(1, 0), lds + 32768 + 16384, tid);
    stage_half(BH(1, 1), lds + 32768 + 24576, tid);
    VMW(4); BAR;                 // T0 landed; T1.B (4 loads) in flight

    bf16x8 bh[4][2];

#pragma unroll 1
    for (int j = 0; j < 7; ++j) {
        const int T = 2 * j;
        PH2(0, 0, 1,
            { stage_half(AH(T + 1, 0), lds + 32768, tid);
              stage_half(AH(T + 1, 1), lds + 32768 + 8192, tid); }, NOP);
        PH2(0, 2, 0,
            { stage_half(BH(T + 2, 0), lds + 16384, tid);
              stage_half(BH(T + 2, 1), lds + 24576, tid); }, VMW(4));
        PH2(32768, 0, 1,
            { stage_half(AH(T + 2, 0), lds + 0, tid);
              stage_half(AH(T + 2, 1), lds + 8192, tid); }, NOP);
        PH2(32768, 2, 0,
            { stage_half(BH(T + 3, 0), lds + 32768 + 16384, tid);
              stage_half(BH(T + 3, 1), lds + 32768 + 24576, tid); }, VMW(4));
    }
    PH2(0, 0, 1,
        { stage_half(AH(15, 0), lds + 32768, tid);
          stage_half(AH(15, 1), lds + 32768 + 8192, tid); }, NOP);
    PH2(0, 2, 0, NOP, VMW(0));
    PH2(32768, 0, 1, NOP, NOP);
    PH2(32768, 2, 0, NOP, NOP);
}

// ------- gate GEMM + fused sigmoid-gate + fused per-chunk scan (scanA) ------

__global__ __launch_bounds__(512, 1) void k_gemm_cat8(
    const u16* __restrict__ A, const u16* __restrict__ Bcat,
    const float* __restrict__ gb, const float* __restrict__ ib,
    u32* __restrict__ ab, float2* __restrict__ cAB) {
    __shared__ __align__(16) u16 lds[65536];
    const int tid = threadIdx.x, lane = tid & 63;
    const int wm = (tid >> 6) >> 2, wn = (tid >> 6) & 3;

    int fid = (int)blockIdx.y * 8 + (int)blockIdx.x;
    int swz = (fid & 7) * 64 + (fid >> 3);
    const long bn = swz & 7, bm = swz >> 3;

    f32x4 acc[8][4] = {};
    pipe256(A + bm * 256 * 1024, Bcat + bn * 256 * 1024, lds, acc, tid);

    const long rbase = bm * 256 + wm * 128;
    const int chbase = (int)bn * 128 + wn * 32;
    float sA[2][8], sB[2][8];
#pragma unroll
    for (int t = 0; t < 2; ++t) {
        int ch = chbase + t * 16 + (lane & 15);
        float g0 = gb[ch], i0 = ib[ch];
#pragma unroll
        for (int m = 0; m < 8; ++m) {
            long row = rbase + m * 16 + ((lane >> 4) << 2);
            float Aseg = 1.0f, Bseg = 0.0f;
#pragma unroll
            for (int i = 0; i < 4; ++i) {
                float pg = acc[m][2 * t][i] + g0;
                float pi = acc[m][2 * t + 1][i] + i0;
                float aa = 1.0f / (1.0f + __expf(-pg));
                float bb = (1.0f - aa) * pi;
                u16 au = f2bf(aa), bu = f2bf(bb);
                ab[(row + i) * 1024 + ch] = (u32)au | ((u32)bu << 16);
                float ar = bf2f(au), br = bf2f(bu);
                Aseg = ar * Aseg;
                Bseg = ar * Bseg + br;
            }
            sA[t][m] = Aseg;
            sB[t][m] = Bseg;
        }
    }
#pragma unroll
    for (int t = 0; t < 2; ++t) {
#pragma unroll
        for (int c2 = 0; c2 < 2; ++c2) {
            float Ac = 1.0f, Bc = 0.0f;
#pragma unroll
            for (int mm = 0; mm < 4; ++mm) {
                int m = c2 * 4 + mm;
#pragma unroll
                for (int q = 0; q < 4; ++q) {
                    float Aq = __shfl(sA[t][m], (lane & 15) + q * 16);
                    float Bq = __shfl(sB[t][m], (lane & 15) + q * 16);
                    Ac = Aq * Ac;
                    Bc = Aq * Bc + Bq;
                }
            }
            if ((lane >> 4) == 0) {
                long gc = (rbase >> 6) + c2;
                int ch = chbase + t * 16 + (lane & 15);
                cAB[gc * 1024 + ch] = make_float2(Ac, Bc);
            }
        }
    }
}

// -------- final GEMM: out = h @ out_w + x + out_b (x residual as bf16) ------

__global__ __launch_bounds__(512, 1) void k_gemm_out8(
    const u16* __restrict__ A, const u16* __restrict__ Bt,
    const u16* __restrict__ xbf, const float* __restrict__ ob,
    float* __restrict__ out) {
    __shared__ __align__(16) u16 lds[65536];
    const int tid = threadIdx.x, lane = tid & 63;
    const int wm = (tid >> 6) >> 2, wn = (tid >> 6) & 3;

    int fid = (int)blockIdx.y * 4 + (int)blockIdx.x;
    int swz = (fid & 7) * 32 + (fid >> 3);
    const long bn = swz & 3, bm = swz >> 2;

    f32x4 acc[8][4] = {};
    pipe256(A + bm * 256 * 1024, Bt + bn * 256 * 1024, lds, acc, tid);

    const long rbase = bm * 256 + wm * 128;
    const int cbase = (int)bn * 256 + wn * 64;
#pragma unroll
    for (int n = 0; n < 4; ++n) {
        int col = cbase + n * 16 + (lane & 15);
        float o0 = ob[col];
#pragma unroll
        for (int m = 0; m < 8; ++m) {
            long row = rbase + m * 16 + ((lane >> 4) << 2);
#pragma unroll
            for (int i = 0; i < 4; ++i) {
                long o = (row + i) * 1024 + col;
                out[o] = acc[m][n][i] + o0 + bf2f(xbf[o]);
            }
        }
    }
}

// ------------- fused prep: cvt_x + transpose_cat + transpose_bf -------------

__global__ __launch_bounds__(256) void k_prep(
    const float4* __restrict__ x4, uint2* __restrict__ xb2,
    const float* __restrict__ gw, const float* __restrict__ iw,
    u16* __restrict__ catW, const float* __restrict__ ow,
    u16* __restrict__ owT) {
    __shared__ float t[32][33];
    int bid = blockIdx.x;
    if (bid < 16384) {
        int i = bid * 256 + threadIdx.x;
        float4 v = x4[i];
        uint2 r;
        r.x = (u32)f2bf(v.x) | ((u32)f2bf(v.y) << 16);
        r.y = (u32)f2bf(v.z) | ((u32)f2bf(v.w) << 16);
        xb2[i] = r;
        return;
    }
    int xi = threadIdx.x & 31, y = threadIdx.x >> 5;
    if (bid < 18432) {
        int q = bid - 16384;
        int c0 = (q & 31) * 32, r0 = ((q >> 5) & 31) * 32, z = q >> 10;
        const float* w = z ? iw : gw;
        for (int i = y; i < 32; i += 8) t[i][xi] = w[(size_t)(r0 + i) * 1024 + c0 + xi];
        __syncthreads();
        for (int i = y; i < 32; i += 8) {
            int ch = c0 + i;
            int r = ((ch >> 4) << 5) | (z << 4) | (ch & 15);
            catW[(size_t)r * 1024 + r0 + xi] = f2bf(t[xi][i]);
        }
    } else {
        int q = bid - 18432;
        int c0 = (q & 31) * 32, r0 = (q >> 5) * 32;
        for (int i = y; i < 32; i += 8) t[i][xi] = ow[(size_t)(r0 + i) * 1024 + c0 + xi];
        __syncthreads();
        for (int i = y; i < 32; i += 8)
            owT[(size_t)(c0 + i) * 1024 + r0 + xi] = f2bf(t[xi][i]);
    }
}

// ---------------- chunked affine scan phases B & C ----------------

__global__ __launch_bounds__(256) void k_scanB(const float2* __restrict__ cAB,
                                               float* __restrict__ hin) {
    int e = blockIdx.x * 256 + threadIdx.x;
    int bt = blockIdx.y;
    float H = 0.f;
#pragma unroll
    for (int c = 0; c < 64; ++c) {
        long s = ((long)bt * 64 + c) * 1024 + e;
        hin[s] = H;
        float2 v = cAB[s];
        H = v.x * H + v.y;
    }
}

__global__ __launch_bounds__(256) void k_scanC(const u32* __restrict__ ab,
                                               const float* __restrict__ hin,
                                               u16* __restrict__ hout) {
    int e = blockIdx.x * 256 + threadIdx.x;
    int c = blockIdx.y, bt = blockIdx.z;
    long base = ((long)bt * 4096 + c * 64) * 1024 + e;
    float H = hin[((long)bt * 64 + c) * 1024 + e];
#pragma unroll 4
    for (int i = 0; i < 64; ++i) {
        u32 v = ab[base + (long)i * 1024];
        H = bf2f((u16)v) * H + bf2f((u16)(v >> 16));
        hout[base + (long)i * 1024] = f2bf(H);
    }
}

// ---------------- launch ----------------

extern "C" void kernel_launch(void* const* d_in, const int* in_sizes, int n_in,
                              void* d_out, int out_size, void* d_ws, size_t ws_size,
                              hipStream_t stream) {
    const float* x      = (const float*)d_in[0];
    const float* gate_w = (const float*)d_in[1];
    const float* gate_b = (const float*)d_in[2];
    const float* inp_w  = (const float*)d_in[3];
    const float* inp_b  = (const float*)d_in[4];
    const float* out_w  = (const float*)d_in[5];
    const float* out_b  = (const float*)d_in[6];
    float* out = (float*)d_out;

    const int Bsz = 4, S = 4096, Din = 1024, Dst = 1024;
    const int M = Bsz * S;                 // 16384

    // workspace layout (bytes)
    char* w = (char*)d_ws;
    u16* xb      = (u16*)(w);                // 33,554,432  x bf16
    u16* catW    = (u16*)(w + 33554432);     //  4,194,304  [gate;inp] interleaved ^T
    u16* owT     = (u16*)(w + 37748736);     //  2,097,152  out_w^T bf16
    u16* hbf     = (u16*)(w + 39845888);     // 33,554,432  scan_out bf16
    float2* cAB  = (float2*)(w + 73400320);  //  2,097,152  chunk (A,H) pairs
    float* hin   = (float*)(w + 75497472);   //  1,048,576  chunk incoming states
    // total 76,546,048 B

    // packed ab lives in d_out (67,108,864 B); overwritten by final GEMM.
    u32* ab = (u32*)d_out;

    // 1. fused prep (cvt + both transposes)
    k_prep<<<19456, 256, 0, stream>>>((const float4*)x, (uint2*)xb,
                                      gate_w, inp_w, catW, out_w, owT);

    // 2. fused concat GEMM -> packed ab + per-chunk scan composition
    k_gemm_cat8<<<dim3(8, M / 256), 512, 0, stream>>>(xb, catW, gate_b, inp_b, ab, cAB);

    // 3. scan combine + replay -> h (bf16)
    k_scanB<<<dim3(4, Bsz), 256, 0, stream>>>(cAB, hin);
    k_scanC<<<dim3(4, 64, Bsz), 256, 0, stream>>>(ab, hin, hbf);

    // 4. final GEMM: out = h @ out_w + x + out_b
    k_gemm_out8<<<dim3(4, M / 256), 512, 0, stream>>>(hbf, owT, xb, out_b, out);
}

// Round 22
// 165.504 us; speedup vs baseline: 1.0856x; 1.0166x over previous
//
#include <hip/hip_runtime.h>

typedef unsigned short u16;
typedef unsigned int   u32;
typedef __bf16 bf16x8 __attribute__((ext_vector_type(8)));
typedef float  f32x4  __attribute__((ext_vector_type(4)));

#define DEVI __device__ __forceinline__

DEVI u16 f2bf(float f) {
    union { float f; u32 u; } c; c.f = f;
    u32 u = c.u;
    u32 r = (u + 0x7fffu + ((u >> 16) & 1u)) >> 16;
    return (u16)r;
}
DEVI float bf2f(u16 v) {
    union { u32 u; float f; } c; c.u = ((u32)v) << 16;
    return c.f;
}

DEVI void gload16(const void* g, void* l) {
    __builtin_amdgcn_global_load_lds(
        (const __attribute__((address_space(1))) void*)g,
        (__attribute__((address_space(3))) void*)l, 16, 0, 0);
}

// ---------------- 256x256 GEMM, ONE fenced sync per K-tile ----------------
// LDS 128KB: buffer q at q*32768 (u16). Halves (16KB, [128 rows][64 K] bf16):
// A0 @+0, A1 @+8192, B0 @+16384, B1 @+24576.
// 3-bit chunk swizzle (r17, measured SQ_LDS_BANK_CONFLICT = 0): physical 16B
// chunk p holds logical p ^ (row&7); stage source ks=((tid&7)^(r&7))<<3,
// reads kA=((lane>>4)^(lane&7))<<3, kB=kA^32.
// r22: r20/r21's NaN was a LEDGER bug (32 tiles staged for K=1024 = 16
// tiles -> OOB reads), not sync. Correct 16-tile schedule: stage
// A(T+1)+B(T+1) during tile T into the opposite buffer; ONE __syncthreads
// per tile close (IR-fenced vmcnt/lgkm drain + barrier; m97 precedent shows
// it drains global_load_lds). Stages are issued >= half a tile (~1400cy)
// before the close > HBM latency, so the drain is near-free. Intra-tile:
// stages hit the opposite buffer, reads the current -> waves free-slip
// across the 24-read + 64-MFMA body (LDS-port/MFMA overlap, T5 diversity).

#define SP1     __builtin_amdgcn_s_setprio(1)
#define SP0     __builtin_amdgcn_s_setprio(0)

DEVI void stage_half(const u16* g, u16* slot, int tid) {
    const int r = tid >> 3;                                  // 0..63
    const int ks = (((tid & 7) ^ (r & 7)) << 3);             // 3-bit pre-swizzle
    gload16(g + (long)r * 1024 + ks, slot + tid * 8);
    gload16(g + (long)(r + 64) * 1024 + ks, slot + 4096 + tid * 8);
}

DEVI f32x4 mfma(const bf16x8& a, const bf16x8& b, const f32x4& c) {
    return __builtin_amdgcn_mfma_f32_16x16x32_bf16(a, b, c, 0, 0, 0);
}

// phase: Q = buffer base, MB = first m-pair (0 or 2). GATE is the only sync.
#define PH2(Q, MB, READB, STG, GATE)                                         \
    {                                                                        \
        if (READB) {                                                         \
            _Pragma("unroll")                                                \
            for (int n = 0; n < 4; ++n) {                                    \
                bh[n][0] = *(const bf16x8*)(lds + (Q) + bbase + n * 1024 + kA); \
                bh[n][1] = *(const bf16x8*)(lds + (Q) + bbase + n * 1024 + kB); \
            }                                                                \
        }                                                                    \
        bf16x8 a0k0 = *(const bf16x8*)(lds + (Q) + abase + (MB) * 2048 + kA); \
        bf16x8 a0k1 = *(const bf16x8*)(lds + (Q) + abase + (MB) * 2048 + kB); \
        bf16x8 a1k0 = *(const bf16x8*)(lds + (Q) + abase + (MB) * 2048 + 1024 + kA); \
        bf16x8 a1k1 = *(const bf16x8*)(lds + (Q) + abase + (MB) * 2048 + 1024 + kB); \
        STG;                                                                 \
        SP1;                                                                 \
        _Pragma("unroll")                                                    \
        for (int n = 0; n < 4; ++n) {                                        \
            acc[(MB) * 2][n]     = mfma(a0k0, bh[n][0], acc[(MB) * 2][n]);   \
            acc[(MB) * 2][n]     = mfma(a0k1, bh[n][1], acc[(MB) * 2][n]);   \
            acc[(MB) * 2 + 1][n] = mfma(a1k0, bh[n][0], acc[(MB) * 2 + 1][n]); \
            acc[(MB) * 2 + 1][n] = mfma(a1k1, bh[n][1], acc[(MB) * 2 + 1][n]); \
        }                                                                    \
        {                                                                    \
            const int M2 = (MB) + 1;                                         \
            bf16x8 c0k0 = *(const bf16x8*)(lds + (Q) + abase + M2 * 2048 + kA); \
            bf16x8 c0k1 = *(const bf16x8*)(lds + (Q) + abase + M2 * 2048 + kB); \
            bf16x8 c1k0 = *(const bf16x8*)(lds + (Q) + abase + M2 * 2048 + 1024 + kA); \
            bf16x8 c1k1 = *(const bf16x8*)(lds + (Q) + abase + M2 * 2048 + 1024 + kB); \
            _Pragma("unroll")                                                \
            for (int n = 0; n < 4; ++n) {                                    \
                acc[M2 * 2][n]     = mfma(c0k0, bh[n][0], acc[M2 * 2][n]);   \
                acc[M2 * 2][n]     = mfma(c0k1, bh[n][1], acc[M2 * 2][n]);   \
                acc[M2 * 2 + 1][n] = mfma(c1k0, bh[n][0], acc[M2 * 2 + 1][n]); \
                acc[M2 * 2 + 1][n] = mfma(c1k1, bh[n][1], acc[M2 * 2 + 1][n]); \
            }                                                                \
        }                                                                    \
        SP0;                                                                 \
        GATE;                                                                \
    }

#define NOP do {} while (0)
#define TCLOSE { __syncthreads(); }
#define AH(t, h) (Ab + (long)(h) * 131072 + (t) * 64)
#define BH(t, h) (Bb + (long)(h) * 131072 + (t) * 64)

DEVI void pipe256(const u16* Ab, const u16* Bb, u16* lds,
                  f32x4 (&acc)[8][4], int tid) {
    const int lane = tid & 63;
    const int wm = (tid >> 6) >> 2, wn = (tid >> 6) & 3;
    const int kA = (((lane >> 4) ^ (lane & 7)) << 3);
    const int kB = kA ^ 32;
    const int abase = wm * 8192 + (lane & 15) * 64;
    const int bbase = 16384 + (wn >> 1) * 8192 + ((wn & 1) * 64 + (lane & 15)) * 64;

    // prologue: T0 -> buf0, fenced drain
    stage_half(AH(0, 0), lds + 0,     tid);
    stage_half(AH(0, 1), lds + 8192,  tid);
    stage_half(BH(0, 0), lds + 16384, tid);
    stage_half(BH(0, 1), lds + 24576, tid);
    __syncthreads();

    bf16x8 bh[4][2];

#pragma unroll 1
    for (int j = 0; j < 7; ++j) {
        const int T = 2 * j;
        // tile T (buf0): stage T+1 -> buf1
        PH2(0, 0, 1,
            { stage_half(AH(T + 1, 0), lds + 32768, tid);
              stage_half(AH(T + 1, 1), lds + 32768 + 8192, tid); }, NOP);
        PH2(0, 2, 0,
            { stage_half(BH(T + 1, 0), lds + 32768 + 16384, tid);
              stage_half(BH(T + 1, 1), lds + 32768 + 24576, tid); }, TCLOSE);
        // tile T+1 (buf1): stage T+2 -> buf0
        PH2(32768, 0, 1,
            { stage_half(AH(T + 2, 0), lds + 0, tid);
              stage_half(AH(T + 2, 1), lds + 8192, tid); }, NOP);
        PH2(32768, 2, 0,
            { stage_half(BH(T + 2, 0), lds + 16384, tid);
              stage_half(BH(T + 2, 1), lds + 24576, tid); }, TCLOSE);
    }
    // tile 14 (buf0): stage T15 -> buf1
    PH2(0, 0, 1,
        { stage_half(AH(15, 0), lds + 32768, tid);
          stage_half(AH(15, 1), lds + 32768 + 8192, tid); }, NOP);
    PH2(0, 2, 0,
        { stage_half(BH(15, 0), lds + 32768 + 16384, tid);
          stage_half(BH(15, 1), lds + 32768 + 24576, tid); }, TCLOSE);
    // tile 15 (buf1): no stage, no sync
    PH2(32768, 0, 1, NOP, NOP);
    PH2(32768, 2, 0, NOP, NOP);
}

// ------- gate GEMM + fused sigmoid-gate + fused per-chunk scan (scanA) ------

__global__ __launch_bounds__(512, 1) void k_gemm_cat8(
    const u16* __restrict__ A, const u16* __restrict__ Bcat,
    const float* __restrict__ gb, const float* __restrict__ ib,
    u32* __restrict__ ab, float2* __restrict__ cAB) {
    __shared__ __align__(16) u16 lds[65536];
    const int tid = threadIdx.x, lane = tid & 63;
    const int wm = (tid >> 6) >> 2, wn = (tid >> 6) & 3;

    int fid = (int)blockIdx.y * 8 + (int)blockIdx.x;
    int swz = (fid & 7) * 64 + (fid >> 3);
    const long bn = swz & 7, bm = swz >> 3;

    f32x4 acc[8][4] = {};
    pipe256(A + bm * 256 * 1024, Bcat + bn * 256 * 1024, lds, acc, tid);

    const long rbase = bm * 256 + wm * 128;
    const int chbase = (int)bn * 128 + wn * 32;
    float sA[2][8], sB[2][8];
#pragma unroll
    for (int t = 0; t < 2; ++t) {
        int ch = chbase + t * 16 + (lane & 15);
        float g0 = gb[ch], i0 = ib[ch];
#pragma unroll
        for (int m = 0; m < 8; ++m) {
            long row = rbase + m * 16 + ((lane >> 4) << 2);
            float Aseg = 1.0f, Bseg = 0.0f;
#pragma unroll
            for (int i = 0; i < 4; ++i) {
                float pg = acc[m][2 * t][i] + g0;
                float pi = acc[m][2 * t + 1][i] + i0;
                float aa = 1.0f / (1.0f + __expf(-pg));
                float bb = (1.0f - aa) * pi;
                u16 au = f2bf(aa), bu = f2bf(bb);
                ab[(row + i) * 1024 + ch] = (u32)au | ((u32)bu << 16);
                float ar = bf2f(au), br = bf2f(bu);
                Aseg = ar * Aseg;
                Bseg = ar * Bseg + br;
            }
            sA[t][m] = Aseg;
            sB[t][m] = Bseg;
        }
    }
#pragma unroll
    for (int t = 0; t < 2; ++t) {
#pragma unroll
        for (int c2 = 0; c2 < 2; ++c2) {
            float Ac = 1.0f, Bc = 0.0f;
#pragma unroll
            for (int mm = 0; mm < 4; ++mm) {
                int m = c2 * 4 + mm;
#pragma unroll
                for (int q = 0; q < 4; ++q) {
                    float Aq = __shfl(sA[t][m], (lane & 15) + q * 16);
                    float Bq = __shfl(sB[t][m], (lane & 15) + q * 16);
                    Ac = Aq * Ac;
                    Bc = Aq * Bc + Bq;
                }
            }
            if ((lane >> 4) == 0) {
                long gc = (rbase >> 6) + c2;
                int ch = chbase + t * 16 + (lane & 15);
                cAB[gc * 1024 + ch] = make_float2(Ac, Bc);
            }
        }
    }
}

// -------- final GEMM: out = h @ out_w + x + out_b (x residual as bf16) ------

__global__ __launch_bounds__(512, 1) void k_gemm_out8(
    const u16* __restrict__ A, const u16* __restrict__ Bt,
    const u16* __restrict__ xbf, const float* __restrict__ ob,
    float* __restrict__ out) {
    __shared__ __align__(16) u16 lds[65536];
    const int tid = threadIdx.x, lane = tid & 63;
    const int wm = (tid >> 6) >> 2, wn = (tid >> 6) & 3;

    int fid = (int)blockIdx.y * 4 + (int)blockIdx.x;
    int swz = (fid & 7) * 32 + (fid >> 3);
    const long bn = swz & 3, bm = swz >> 2;

    f32x4 acc[8][4] = {};
    pipe256(A + bm * 256 * 1024, Bt + bn * 256 * 1024, lds, acc, tid);

    const long rbase = bm * 256 + wm * 128;
    const int cbase = (int)bn * 256 + wn * 64;
#pragma unroll
    for (int n = 0; n < 4; ++n) {
        int col = cbase + n * 16 + (lane & 15);
        float o0 = ob[col];
#pragma unroll
        for (int m = 0; m < 8; ++m) {
            long row = rbase + m * 16 + ((lane >> 4) << 2);
#pragma unroll
            for (int i = 0; i < 4; ++i) {
                long o = (row + i) * 1024 + col;
                out[o] = acc[m][n][i] + o0 + bf2f(xbf[o]);
            }
        }
    }
}

// ------------- fused prep: cvt_x + transpose_cat + transpose_bf -------------

__global__ __launch_bounds__(256) void k_prep(
    const float4* __restrict__ x4, uint2* __restrict__ xb2,
    const float* __restrict__ gw, const float* __restrict__ iw,
    u16* __restrict__ catW, const float* __restrict__ ow,
    u16* __restrict__ owT) {
    __shared__ float t[32][33];
    int bid = blockIdx.x;
    if (bid < 16384) {
        int i = bid * 256 + threadIdx.x;
        float4 v = x4[i];
        uint2 r;
        r.x = (u32)f2bf(v.x) | ((u32)f2bf(v.y) << 16);
        r.y = (u32)f2bf(v.z) | ((u32)f2bf(v.w) << 16);
        xb2[i] = r;
        return;
    }
    int xi = threadIdx.x & 31, y = threadIdx.x >> 5;
    if (bid < 18432) {
        int q = bid - 16384;
        int c0 = (q & 31) * 32, r0 = ((q >> 5) & 31) * 32, z = q >> 10;
        const float* w = z ? iw : gw;
        for (int i = y; i < 32; i += 8) t[i][xi] = w[(size_t)(r0 + i) * 1024 + c0 + xi];
        __syncthreads();
        for (int i = y; i < 32; i += 8) {
            int ch = c0 + i;
            int r = ((ch >> 4) << 5) | (z << 4) | (ch & 15);
            catW[(size_t)r * 1024 + r0 + xi] = f2bf(t[xi][i]);
        }
    } else {
        int q = bid - 18432;
        int c0 = (q & 31) * 32, r0 = (q >> 5) * 32;
        for (int i = y; i < 32; i += 8) t[i][xi] = ow[(size_t)(r0 + i) * 1024 + c0 + xi];
        __syncthreads();
        for (int i = y; i < 32; i += 8)
            owT[(size_t)(c0 + i) * 1024 + r0 + xi] = f2bf(t[xi][i]);
    }
}

// ---------------- chunked affine scan phases B & C ----------------

__global__ __launch_bounds__(256) void k_scanB(const float2* __restrict__ cAB,
                                               float* __restrict__ hin) {
    int e = blockIdx.x * 256 + threadIdx.x;
    int bt = blockIdx.y;
    float H = 0.f;
#pragma unroll
    for (int c = 0; c < 64; ++c) {
        long s = ((long)bt * 64 + c) * 1024 + e;
        hin[s] = H;
        float2 v = cAB[s];
        H = v.x * H + v.y;
    }
}

__global__ __launch_bounds__(256) void k_scanC(const u32* __restrict__ ab,
                                               const float* __restrict__ hin,
                                               u16* __restrict__ hout) {
    int e = blockIdx.x * 256 + threadIdx.x;
    int c = blockIdx.y, bt = blockIdx.z;
    long base = ((long)bt * 4096 + c * 64) * 1024 + e;
    float H = hin[((long)bt * 64 + c) * 1024 + e];
#pragma unroll 4
    for (int i = 0; i < 64; ++i) {
        u32 v = ab[base + (long)i * 1024];
        H = bf2f((u16)v) * H + bf2f((u16)(v >> 16));
        hout[base + (long)i * 1024] = f2bf(H);
    }
}

// ---------------- launch ----------------

extern "C" void kernel_launch(void* const* d_in, const int* in_sizes, int n_in,
                              void* d_out, int out_size, void* d_ws, size_t ws_size,
                              hipStream_t stream) {
    const float* x      = (const float*)d_in[0];
    const float* gate_w = (const float*)d_in[1];
    const float* gate_b = (const float*)d_in[2];
    const float* inp_w  = (const float*)d_in[3];
    const float* inp_b  = (const float*)d_in[4];
    const float* out_w  = (const float*)d_in[5];
    const float* out_b  = (const float*)d_in[6];
    float* out = (float*)d_out;

    const int Bsz = 4, S = 4096, Din = 1024, Dst = 1024;
    const int M = Bsz * S;                 // 16384

    // workspace layout (bytes)
    char* w = (char*)d_ws;
    u16* xb      = (u16*)(w);                // 33,554,432  x bf16
    u16* catW    = (u16*)(w + 33554432);     //  4,194,304  [gate;inp] interleaved ^T
    u16* owT     = (u16*)(w + 37748736);     //  2,097,152  out_w^T bf16
    u16* hbf     = (u16*)(w + 39845888);     // 33,554,432  scan_out bf16
    float2* cAB  = (float2*)(w + 73400320);  //  2,097,152  chunk (A,H) pairs
    float* hin   = (float*)(w + 75497472);   //  1,048,576  chunk incoming states
    // total 76,546,048 B

    // packed ab lives in d_out (67,108,864 B); overwritten by final GEMM.
    u32* ab = (u32*)d_out;

    // 1. fused prep (cvt + both transposes)
    k_prep<<<19456, 256, 0, stream>>>((const float4*)x, (uint2*)xb,
                                      gate_w, inp_w, catW, out_w, owT);

    // 2. fused concat GEMM -> packed ab + per-chunk scan composition
    k_gemm_cat8<<<dim3(8, M / 256), 512, 0, stream>>>(xb, catW, gate_b, inp_b, ab, cAB);

    // 3. scan combine + replay -> h (bf16)
    k_scanB<<<dim3(4, Bsz), 256, 0, stream>>>(cAB, hin);
    k_scanC<<<dim3(4, 64, Bsz), 256, 0, stream>>>(ab, hin, hbf);

    // 4. final GEMM: out = h @ out_w + x + out_b
    k_gemm_out8<<<dim3(4, M / 256), 512, 0, stream>>>(hbf, owT, xb, out_b, out);
}

// Round 23
// 162.616 us; speedup vs baseline: 1.1049x; 1.0178x over previous
//
#include <hip/hip_runtime.h>

typedef unsigned short u16;
typedef unsigned int   u32;
typedef __bf16 bf16x8 __attribute__((ext_vector_type(8)));
typedef float  f32x4  __attribute__((ext_vector_type(4)));

#define DEVI __device__ __forceinline__

DEVI u16 f2bf(float f) {
    union { float f; u32 u; } c; c.f = f;
    u32 u = c.u;
    u32 r = (u + 0x7fffu + ((u >> 16) & 1u)) >> 16;
    return (u16)r;
}
DEVI float bf2f(u16 v) {
    union { u32 u; float f; } c; c.u = ((u32)v) << 16;
    return c.f;
}

DEVI void gload16(const void* g, void* l) {
    __builtin_amdgcn_global_load_lds(
        (const __attribute__((address_space(1))) void*)g,
        (__attribute__((address_space(3))) void*)l, 16, 0, 0);
}

// ------------- 128x128 GEMM, 256 threads, 2 blocks/CU -------------
// The r22 structure (3-bit swizzle: conflicts=0; one __syncthreads per
// K-tile; stage-first; setprio) shrunk to a 64KB-LDS / ~185-reg block so
// TWO independent blocks co-reside per CU: inter-block slip hides the
// latency that the single-block 512-thread variants (all pinned at
// ~840 TF) could not (m114).
// Buffer q at q*16384 u16 (32KB): A half [128 rows][64 K] @+0 (8192 u16),
// B half @+8192. Swizzle: physical 16B chunk p holds logical p^(row&7);
// stage source ks=((tid&7)^((tid>>3)&7))<<3 (rows j*32+(tid>>3) keep r&7);
// reads kA=((lane>>4)^(lane&7))<<3, kB=kA^32 (all frag-row offsets are
// multiples of 8 -> row&7 == lane&7 everywhere, same algebra as r17).

#define SP1     __builtin_amdgcn_s_setprio(1)
#define SP0     __builtin_amdgcn_s_setprio(0)

// stage one 16KB half ([128 rows][64 K] bf16) with 256 threads: 4 x 16B.
// Round j fills rows j*32..j*32+31; dest linear (j*2048 + tid*8 u16).
DEVI void stage128(const u16* g, u16* slot, int tid) {
    const int ks = (((tid & 7) ^ ((tid >> 3) & 7)) << 3);
#pragma unroll
    for (int j = 0; j < 4; ++j) {
        const int r = j * 32 + (tid >> 3);
        gload16(g + (long)r * 1024 + ks, slot + j * 2048 + tid * 8);
    }
}

DEVI f32x4 mfma(const bf16x8& a, const bf16x8& b, const f32x4& c) {
    return __builtin_amdgcn_mfma_f32_16x16x32_bf16(a, b, c, 0, 0, 0);
}

#define NOP do {} while (0)
#define TCLOSE { __syncthreads(); }

// one K-tile from buffer base Q: stage first, 16 reads, 32 MFMA, sync.
#define TILE(Q, STG, SYNC)                                                   \
    {                                                                        \
        STG;                                                                 \
        bf16x8 bh0[4], bh1[4], aa0[4], aa1[4];                               \
        _Pragma("unroll")                                                    \
        for (int n = 0; n < 4; ++n) {                                        \
            bh0[n] = *(const bf16x8*)(lds + (Q) + bbase + n * 1024 + kA);    \
            bh1[n] = *(const bf16x8*)(lds + (Q) + bbase + n * 1024 + kB);    \
        }                                                                    \
        _Pragma("unroll")                                                    \
        for (int m = 0; m < 4; ++m) {                                        \
            aa0[m] = *(const bf16x8*)(lds + (Q) + abase + m * 1024 + kA);    \
            aa1[m] = *(const bf16x8*)(lds + (Q) + abase + m * 1024 + kB);    \
        }                                                                    \
        SP1;                                                                 \
        _Pragma("unroll")                                                    \
        for (int m = 0; m < 4; ++m) {                                        \
            _Pragma("unroll")                                                \
            for (int n = 0; n < 4; ++n) {                                    \
                acc[m][n] = mfma(aa0[m], bh0[n], acc[m][n]);                 \
                acc[m][n] = mfma(aa1[m], bh1[n], acc[m][n]);                 \
            }                                                                \
        }                                                                    \
        SP0;                                                                 \
        SYNC;                                                                \
    }

#define STA(t, buf) stage128(Ab + (t) * 64, lds + (buf), tid)
#define STB(t, buf) stage128(Bb + (t) * 64, lds + (buf) + 8192, tid)

DEVI void pipe128(const u16* Ab, const u16* Bb, u16* lds,
                  f32x4 (&acc)[4][4], int tid) {
    const int lane = tid & 63;
    const int wm = (tid >> 6) >> 1, wn = (tid >> 6) & 1;
    const int kA = (((lane >> 4) ^ (lane & 7)) << 3);
    const int kB = kA ^ 32;
    const int abase = wm * 4096 + (lane & 15) * 64;
    const int bbase = 8192 + wn * 4096 + (lane & 15) * 64;

    // prologue: T0 -> buf0
    STA(0, 0); STB(0, 0);
    __syncthreads();

#pragma unroll 1
    for (int j = 0; j < 7; ++j) {
        const int T = 2 * j;
        TILE(0,     { STA(T + 1, 16384); STB(T + 1, 16384); }, TCLOSE);
        TILE(16384, { STA(T + 2, 0);     STB(T + 2, 0);     }, TCLOSE);
    }
    TILE(0,     { STA(15, 16384); STB(15, 16384); }, TCLOSE);
    TILE(16384, NOP, NOP);
}

// ------- gate GEMM + fused sigmoid-gate + fused per-chunk scan (scanA) ------
// 128x128 tile: wave (wm,wn) owns rows bm*128+wm*64..+64 (= ONE 64-row
// chunk) x 64 concat-cols (32 channels). Frag n even = gate, odd = inp.

__global__ __launch_bounds__(256, 2) void k_gemm_cat8(
    const u16* __restrict__ A, const u16* __restrict__ Bcat,
    const float* __restrict__ gb, const float* __restrict__ ib,
    u32* __restrict__ ab, float2* __restrict__ cAB) {
    __shared__ __align__(16) u16 lds[32768];     // 64KB -> 2 blocks/CU
    const int tid = threadIdx.x, lane = tid & 63;
    const int wm = (tid >> 6) >> 1, wn = (tid >> 6) & 1;

    // bijective XCD swizzle, grid (16, 128) = 2048 wg
    int fid = (int)blockIdx.y * 16 + (int)blockIdx.x;
    int swz = (fid & 7) * 256 + (fid >> 3);
    const long bn = swz & 15, bm = swz >> 4;

    f32x4 acc[4][4] = {};
    pipe128(A + bm * 128 * 1024, Bcat + bn * 128 * 1024, lds, acc, tid);

    const long rbase = bm * 128 + wm * 64;
    const int chbase = (int)bn * 64 + wn * 32;
    float sA[2][4], sB[2][4];
#pragma unroll
    for (int t = 0; t < 2; ++t) {
        int ch = chbase + t * 16 + (lane & 15);
        float g0 = gb[ch], i0 = ib[ch];
#pragma unroll
        for (int m = 0; m < 4; ++m) {
            long row = rbase + m * 16 + ((lane >> 4) << 2);
            float Aseg = 1.0f, Bseg = 0.0f;
#pragma unroll
            for (int i = 0; i < 4; ++i) {
                float pg = acc[m][2 * t][i] + g0;
                float pi = acc[m][2 * t + 1][i] + i0;
                float aa = 1.0f / (1.0f + __expf(-pg));
                float bb = (1.0f - aa) * pi;
                u16 au = f2bf(aa), bu = f2bf(bb);
                ab[(row + i) * 1024 + ch] = (u32)au | ((u32)bu << 16);
                float ar = bf2f(au), br = bf2f(bu);
                Aseg = ar * Aseg;
                Bseg = ar * Bseg + br;
            }
            sA[t][m] = Aseg;
            sB[t][m] = Bseg;
        }
    }
    // compose the wave's single 64-row chunk: fold m (rows m*16+) then q (+4)
#pragma unroll
    for (int t = 0; t < 2; ++t) {
        float Ac = 1.0f, Bc = 0.0f;
#pragma unroll
        for (int m = 0; m < 4; ++m) {
#pragma unroll
            for (int q = 0; q < 4; ++q) {
                float Aq = __shfl(sA[t][m], (lane & 15) + q * 16);
                float Bq = __shfl(sB[t][m], (lane & 15) + q * 16);
                Ac = Aq * Ac;
                Bc = Aq * Bc + Bq;
            }
        }
        if ((lane >> 4) == 0) {
            long gc = rbase >> 6;                 // = bm*2 + wm
            int ch = chbase + t * 16 + (lane & 15);
            cAB[gc * 1024 + ch] = make_float2(Ac, Bc);
        }
    }
}

// -------- final GEMM: out = h @ out_w + x + out_b (x residual as bf16) ------

__global__ __launch_bounds__(256, 2) void k_gemm_out8(
    const u16* __restrict__ A, const u16* __restrict__ Bt,
    const u16* __restrict__ xbf, const float* __restrict__ ob,
    float* __restrict__ out) {
    __shared__ __align__(16) u16 lds[32768];
    const int tid = threadIdx.x, lane = tid & 63;
    const int wm = (tid >> 6) >> 1, wn = (tid >> 6) & 1;

    // bijective XCD swizzle, grid (8, 128) = 1024 wg
    int fid = (int)blockIdx.y * 8 + (int)blockIdx.x;
    int swz = (fid & 7) * 128 + (fid >> 3);
    const long bn = swz & 7, bm = swz >> 3;

    f32x4 acc[4][4] = {};
    pipe128(A + bm * 128 * 1024, Bt + bn * 128 * 1024, lds, acc, tid);

    const long rbase = bm * 128 + wm * 64;
    const int cbase = (int)bn * 128 + wn * 64;
#pragma unroll
    for (int n = 0; n < 4; ++n) {
        int col = cbase + n * 16 + (lane & 15);
        float o0 = ob[col];
#pragma unroll
        for (int m = 0; m < 4; ++m) {
            long row = rbase + m * 16 + ((lane >> 4) << 2);
#pragma unroll
            for (int i = 0; i < 4; ++i) {
                long o = (row + i) * 1024 + col;
                out[o] = acc[m][n][i] + o0 + bf2f(xbf[o]);
            }
        }
    }
}

// ------------- fused prep: cvt_x + transpose_cat + transpose_bf -------------

__global__ __launch_bounds__(256) void k_prep(
    const float4* __restrict__ x4, uint2* __restrict__ xb2,
    const float* __restrict__ gw, const float* __restrict__ iw,
    u16* __restrict__ catW, const float* __restrict__ ow,
    u16* __restrict__ owT) {
    __shared__ float t[32][33];
    int bid = blockIdx.x;
    if (bid < 16384) {
        int i = bid * 256 + threadIdx.x;
        float4 v = x4[i];
        uint2 r;
        r.x = (u32)f2bf(v.x) | ((u32)f2bf(v.y) << 16);
        r.y = (u32)f2bf(v.z) | ((u32)f2bf(v.w) << 16);
        xb2[i] = r;
        return;
    }
    int xi = threadIdx.x & 31, y = threadIdx.x >> 5;
    if (bid < 18432) {
        int q = bid - 16384;
        int c0 = (q & 31) * 32, r0 = ((q >> 5) & 31) * 32, z = q >> 10;
        const float* w = z ? iw : gw;
        for (int i = y; i < 32; i += 8) t[i][xi] = w[(size_t)(r0 + i) * 1024 + c0 + xi];
        __syncthreads();
        for (int i = y; i < 32; i += 8) {
            int ch = c0 + i;
            int r = ((ch >> 4) << 5) | (z << 4) | (ch & 15);
            catW[(size_t)r * 1024 + r0 + xi] = f2bf(t[xi][i]);
        }
    } else {
        int q = bid - 18432;
        int c0 = (q & 31) * 32, r0 = (q >> 5) * 32;
        for (int i = y; i < 32; i += 8) t[i][xi] = ow[(size_t)(r0 + i) * 1024 + c0 + xi];
        __syncthreads();
        for (int i = y; i < 32; i += 8)
            owT[(size_t)(c0 + i) * 1024 + r0 + xi] = f2bf(t[xi][i]);
    }
}

// ---------------- chunked affine scan phases B & C ----------------

__global__ __launch_bounds__(256) void k_scanB(const float2* __restrict__ cAB,
                                               float* __restrict__ hin) {
    int e = blockIdx.x * 256 + threadIdx.x;
    int bt = blockIdx.y;
    float H = 0.f;
#pragma unroll
    for (int c = 0; c < 64; ++c) {
        long s = ((long)bt * 64 + c) * 1024 + e;
        hin[s] = H;
        float2 v = cAB[s];
        H = v.x * H + v.y;
    }
}

__global__ __launch_bounds__(256) void k_scanC(const u32* __restrict__ ab,
                                               const float* __restrict__ hin,
                                               u16* __restrict__ hout) {
    int e = blockIdx.x * 256 + threadIdx.x;
    int c = blockIdx.y, bt = blockIdx.z;
    long base = ((long)bt * 4096 + c * 64) * 1024 + e;
    float H = hin[((long)bt * 64 + c) * 1024 + e];
#pragma unroll 4
    for (int i = 0; i < 64; ++i) {
        u32 v = ab[base + (long)i * 1024];
        H = bf2f((u16)v) * H + bf2f((u16)(v >> 16));
        hout[base + (long)i * 1024] = f2bf(H);
    }
}

// ---------------- launch ----------------

extern "C" void kernel_launch(void* const* d_in, const int* in_sizes, int n_in,
                              void* d_out, int out_size, void* d_ws, size_t ws_size,
                              hipStream_t stream) {
    const float* x      = (const float*)d_in[0];
    const float* gate_w = (const float*)d_in[1];
    const float* gate_b = (const float*)d_in[2];
    const float* inp_w  = (const float*)d_in[3];
    const float* inp_b  = (const float*)d_in[4];
    const float* out_w  = (const float*)d_in[5];
    const float* out_b  = (const float*)d_in[6];
    float* out = (float*)d_out;

    const int Bsz = 4, S = 4096, Din = 1024, Dst = 1024;
    const int M = Bsz * S;                 // 16384

    // workspace layout (bytes)
    char* w = (char*)d_ws;
    u16* xb      = (u16*)(w);                // 33,554,432  x bf16
    u16* catW    = (u16*)(w + 33554432);     //  4,194,304  [gate;inp] interleaved ^T
    u16* owT     = (u16*)(w + 37748736);     //  2,097,152  out_w^T bf16
    u16* hbf     = (u16*)(w + 39845888);     // 33,554,432  scan_out bf16
    float2* cAB  = (float2*)(w + 73400320);  //  2,097,152  chunk (A,H) pairs
    float* hin   = (float*)(w + 75497472);   //  1,048,576  chunk incoming states
    // total 76,546,048 B

    // packed ab lives in d_out (67,108,864 B); overwritten by final GEMM.
    u32* ab = (u32*)d_out;

    // 1. fused prep (cvt + both transposes)
    k_prep<<<19456, 256, 0, stream>>>((const float4*)x, (uint2*)xb,
                                      gate_w, inp_w, catW, out_w, owT);

    // 2. fused concat GEMM -> packed ab + per-chunk scan composition
    k_gemm_cat8<<<dim3(16, M / 128), 256, 0, stream>>>(xb, catW, gate_b, inp_b, ab, cAB);

    // 3. scan combine + replay -> h (bf16)
    k_scanB<<<dim3(4, Bsz), 256, 0, stream>>>(cAB, hin);
    k_scanC<<<dim3(4, 64, Bsz), 256, 0, stream>>>(ab, hin, hbf);

    // 4. final GEMM: out = h @ out_w + x + out_b
    k_gemm_out8<<<dim3(8, M / 128), 256, 0, stream>>>(hbf, owT, xb, out_b, out);
}